// Round 5
// baseline (666.648 us; speedup 1.0000x reference)
//
#include <hip/hip_runtime.h>
#include <hip/hip_bf16.h>
#include <stdint.h>

// MobileViTBlockV2: B=16, C=256, H=W=64, D=256, F=512, L=2, patch 2x2.
// R9: base = R8 (verified 623.8us, GN folded into GEMMs). Single change:
// GEMM K-loop is now 1-deep stage-ahead double-buffered (T3 minimum 2-phase):
// issue global_load_lds for tile t+1 into the idle LDS buffer BEFORE the MFMA
// compute of tile t; the compiler-emitted vmcnt(0) drain at the end-of-iter
// __syncthreads() completes the prefetch. 1 barrier/step instead of 2; HBM
// latency hides under compute. LDS 64KB -> 2 blocks/CU (was ~1.5 effective).

#define B_    16
#define C_    256
#define D_    256
#define NPIX  4096
#define NE_PB 1048576   // D_*NPIX elements per batch for GN

typedef __attribute__((ext_vector_type(8))) short  short8;
typedef __attribute__((ext_vector_type(4))) short  short4v;
typedef __attribute__((ext_vector_type(4))) float  f32x4;
typedef __attribute__((ext_vector_type(2))) float  f32x2;

__device__ __forceinline__ float b2f(short s){
  return __uint_as_float(((unsigned)(unsigned short)s) << 16);
}
__device__ __forceinline__ short f2b(float f){
  unsigned u = __float_as_uint(f);
  return (short)((u + 0x7fffu + ((u >> 16) & 1u)) >> 16);  // RNE
}
__device__ __forceinline__ float silu_f(float x){ return x / (1.f + expf(-x)); }

__device__ __forceinline__ void gld16(const short* g, short* l){
  __builtin_amdgcn_global_load_lds(
      (const __attribute__((address_space(1))) void*)g,
      (__attribute__((address_space(3))) void*)l, 16, 0, 0);
}

// pi (parity-permuted) -> pixel: pi = parity*1024 + (h/2)*32 + (w/2)
__device__ __forceinline__ int pi2pix(int n){
  int p = n >> 10, idx = n & 1023;
  int h = ((idx >> 5) << 1) | (p >> 1);
  int w = ((idx & 31) << 1) | (p & 1);
  return h*64 + w;
}

// ---------- all weight casts (g-scaled at fold sites) + stats zero ----------
__global__ void cvt6_k(const float* __restrict__ s0, const float* __restrict__ s1,
                       const float* __restrict__ s2, const float* __restrict__ s3,
                       const float* __restrict__ s4, const float* __restrict__ s5,
                       const float* __restrict__ g1, const float* __restrict__ g2,
                       const float* __restrict__ gf,
                       short* __restrict__ dst, float* __restrict__ stats){
  const int i = blockIdx.x*256 + threadIdx.x;
  if (blockIdx.x == 0 && threadIdx.x < 160) stats[threadIdx.x] = 0.f;
  if (i >= 1049088) return;
  float v;
  if      (i <  65536){ v = s0[i]; }                                    // pw
  else if (i < 328192){ int j = i -  65536;                             // qkv (fold gn1)
                        v = s1[j] * g1[(j/131328)*256 + (j & 255)]; }
  else if (i < 459264){ v = s2[i - 328192]; }                           // out
  else if (i < 721408){ int j = i - 459264;                             // ffn1 (fold gn2)
                        v = s3[j] * g2[(j >> 17)*256 + (j & 255)]; }
  else if (i < 983552){ v = s4[i - 721408]; }                           // ffn2
  else               { int j = i - 983552;                              // proj (fold gnf)
                        v = s5[j] * gf[j & 255]; }
  dst[i] = f2b(v);
}

// ---------- per-site u = W.g, v = W.b  (one wave per output row) ----------
// rows: [0,1026) qkv L0/L1 (513 each, row0=q) ; [1026,2050) ffn1 L0/L1 ;
// [2050,2306) proj. uv[row*2] = u, uv[row*2+1] = v.
__global__ void fold_k(const float* __restrict__ qkvw, const float* __restrict__ f1w,
                       const float* __restrict__ pjw,
                       const float* __restrict__ g1, const float* __restrict__ b1,
                       const float* __restrict__ g2, const float* __restrict__ b2,
                       const float* __restrict__ gf, const float* __restrict__ bf,
                       float* __restrict__ uv){
  const int row = blockIdx.x;
  const int l = threadIdx.x;
  const float* W; const float* g; const float* bb;
  if (row < 1026){ int layer = row/513, o = row - layer*513;
    W = qkvw + (size_t)(layer*513 + o)*256; g = g1 + layer*256; bb = b1 + layer*256; }
  else if (row < 2050){ int r2 = row - 1026; int layer = r2 >> 9, o = r2 & 511;
    W = f1w + (size_t)(layer*512 + o)*256; g = g2 + layer*256; bb = b2 + layer*256; }
  else { int o = row - 2050; W = pjw + (size_t)o*256; g = gf; bb = bf; }
  float u = 0.f, v = 0.f;
#pragma unroll
  for (int k = 0; k < 4; ++k){
    const int c = l + k*64;
    const float w = W[c];
    u += w * g[c]; v += w * bb[c];
  }
#pragma unroll
  for (int o = 32; o > 0; o >>= 1){ u += __shfl_down(u, o); v += __shfl_down(v, o); }
  if (l == 0){ uv[row*2] = u; uv[row*2+1] = v; }
}

// ---------- dwconv3x3 + BN + SiLU: one block per (b,c) plane ----------
__global__ __launch_bounds__(256)
void dwconv_k(const float* __restrict__ X, const float* __restrict__ W,
              const float* __restrict__ G, const float* __restrict__ Bb,
              const float* __restrict__ Mn, const float* __restrict__ Vr,
              short* __restrict__ O){
  const int c = blockIdx.x, b = blockIdx.y;
  const int t = threadIdx.x;
  __shared__ float xs[66][68];
  // halo zero
  if (t < 132){ int r = (t >= 66) ? 65 : 0; int cc = (t >= 66) ? t-66 : t; xs[r][cc] = 0.f; }
  if (t < 128){ int r = 1 + (t & 63); int cc = (t >> 6) ? 65 : 0; xs[r][cc] = 0.f; }
  const float* xp = X + ((size_t)(b*C_ + c)) * NPIX;
#pragma unroll
  for (int it = 0; it < 4; ++it){
    const int idx = it*256 + t;
    const int row = idx >> 4, cq = idx & 15;
    f32x4 v = *(const f32x4*)&xp[row*64 + cq*4];
    xs[row+1][cq*4+1] = v.x; xs[row+1][cq*4+2] = v.y;
    xs[row+1][cq*4+3] = v.z; xs[row+1][cq*4+4] = v.w;
  }
  float wgt[9];
#pragma unroll
  for (int j = 0; j < 9; ++j) wgt[j] = W[c*9 + j];
  const float scale = G[c] * rsqrtf(Vr[c] + 1e-5f);
  const float mu = Mn[c], bb = Bb[c];
  __syncthreads();
  const int tr = t >> 4, tc = t & 15;
  float win[6][6];
#pragma unroll
  for (int dr = 0; dr < 6; ++dr){
    f32x4 a = *(const f32x4*)&xs[tr*4+dr][tc*4];
    f32x2 bq = *(const f32x2*)&xs[tr*4+dr][tc*4+4];
    win[dr][0] = a.x; win[dr][1] = a.y; win[dr][2] = a.z; win[dr][3] = a.w;
    win[dr][4] = bq.x; win[dr][5] = bq.y;
  }
  short* op = O + ((size_t)(b*C_ + c)) * NPIX;
#pragma unroll
  for (int jr = 0; jr < 4; ++jr){
    short4v o;
#pragma unroll
    for (int jc = 0; jc < 4; ++jc){
      float s = 0.f;
#pragma unroll
      for (int dh = 0; dh < 3; ++dh)
#pragma unroll
        for (int dw = 0; dw < 3; ++dw)
          s += win[jr+dh][jc+dw] * wgt[dh*3+dw];
      float y = (s - mu) * scale + bb;
      o[jc] = f2b(silu_f(y));
    }
    *(short4v*)&op[(tr*4+jr)*64 + tc*4] = o;
  }
}

// ---------- (b,c,s) -> (b,s,c) bf16 transpose, 64x64 tiles, vector both sides ----------
__global__ void transpose_k(const short* __restrict__ I, short* __restrict__ O){
  const int s0 = blockIdx.x*64, c0 = blockIdx.y*64, b = blockIdx.z;
  const int t = threadIdx.x;
  __shared__ short tile[64][68];   // [s_local][c_local]
  const int hi = t >> 4, lo = t & 15;
#pragma unroll
  for (int cy = 0; cy < 4; ++cy){
    const int cl = cy*16 + hi;
    short4v v = *(const short4v*)&I[((size_t)(b*C_ + c0 + cl))*NPIX + s0 + lo*4];
    tile[lo*4+0][cl] = v.x; tile[lo*4+1][cl] = v.y;
    tile[lo*4+2][cl] = v.z; tile[lo*4+3][cl] = v.w;
  }
  __syncthreads();
#pragma unroll
  for (int py = 0; py < 4; ++py){
    const int pl = py*16 + hi;
    short4v v = *(const short4v*)&tile[pl][lo*4];
    *(short4v*)&O[((size_t)(b*NPIX + s0 + pl))*C_ + c0 + lo*4] = v;
  }
}

// ---------- MFMA bf16 GEMM: D[pix][chan] = sum_k X[pix][k]*Wt[chan][k] ----------
// Tile 128 pix x 128 chan, BK=64, double-buffered (stage t+1 during compute t).
// EPI: 0 = P(bf16)=acc (+stats); 1 = bf16 Obf = acc+bias;
// 2 = P += acc+bias (+stats); 3 = bf16 Obf = silu(acc+bias);
// 4 = f32 NCHW Of32 = BN(acc); 5 = P += acc+bias at pi2pix(row) (+stats)
// FOLD: GN folded input — epilogue out = acc*inv + (bias + v - inv*mu*u).
// GATHER: stage X rows at pi2pix(row) (per-lane global address).
template<int EPI, int K, int FOLD, int GATHER>
__global__ __launch_bounds__(256, 2)
void gemm_k(const short* __restrict__ Wt, const short* __restrict__ X,
            const int M,
            const float* __restrict__ bias,
            short* __restrict__ P,
            short* __restrict__ Obf,
            float* __restrict__ Of32,
            const float* __restrict__ bng, const float* __restrict__ bnb,
            const float* __restrict__ bnm, const float* __restrict__ bnv,
            float* __restrict__ st,
            const float* __restrict__ uv, const float* __restrict__ stIn)
{
  constexpr int S = K / 64;
  const int nt = blockIdx.x;          // pixel tile (128)
  const int ct = blockIdx.y;          // chan tile (128)
  const int b  = blockIdx.z;
  const int tid = threadIdx.x;
  const int ln = tid & 63, wv = tid >> 6;
  const int wx = wv & 1;              // chan half (64)
  const int wy = wv >> 1;             // pixel half (64)
  const int lr = ln & 15, lq = ln >> 4;
  const int rl = ln >> 3, sp = ln & 7;
  const int sw = sp ^ rl;             // staged k-seg (XOR swizzle)

  // double-buffered staging: buf b at byte 32768*b; As 16KB + Xs 16KB each
  __shared__ __align__(16) char smem[65536];
  float* CT = (float*)smem;            // epilogue restage (64x132 f32, 33792 B)
  float* red = (float*)(smem + 33792); // 8 floats

  const short* Wp = Wt + (size_t)(ct*128)*K;
  const short* Xp = X + ((size_t)b*NPIX + (size_t)nt*128) * K;

  const short* gw[4]; const short* gx[4]; int lo4[4];
#pragma unroll
  for (int j = 0; j < 4; ++j){
    const int row = 32*wv + 8*j + rl;
    gw[j] = Wp + (size_t)row*K + sw*8;
    if constexpr (GATHER)
      gx[j] = X + ((size_t)b*NPIX + pi2pix(nt*128 + row))*K + sw*8;
    else
      gx[j] = Xp + (size_t)row*K + sw*8;
    lo4[j] = (4*wv + j)*512;           // shorts within a 16KB half-buffer
  }

  auto stage = [&](int stp){
    short* as = (short*)smem + ((stp & 1) ? 16384 : 0);   // 32768 B stride
    short* xs = as + 8192;                                 // +16384 B
#pragma unroll
    for (int j = 0; j < 4; ++j) gld16(gw[j] + stp*64, as + lo4[j]);
#pragma unroll
    for (int j = 0; j < 4; ++j) gld16(gx[j] + stp*64, xs + lo4[j]);
  };

  f32x4 acc[4][4];
#pragma unroll
  for (int r = 0; r < 4; ++r)
#pragma unroll
    for (int c = 0; c < 4; ++c) acc[r][c] = (f32x4){0.f,0.f,0.f,0.f};

  stage(0);
  __syncthreads();                     // compiler emits vmcnt(0) drain here
  for (int stp = 0; stp < S; ++stp){
    if (stp + 1 < S) stage(stp + 1);   // prefetch next tile into idle buffer
    const char* asb = (const char*)smem + ((stp & 1) << 15);
    const char* xsb = asb + 16384;
#pragma unroll
    for (int kk = 0; kk < 2; ++kk){
      const int seg = ((kk*4 + lq) ^ (lr & 7)) * 16;   // byte offset in 128B row
      short8 aw[4], bx[4];
#pragma unroll
      for (int r = 0; r < 4; ++r)
        aw[r] = *(const short8*)(asb + (wx*64 + r*16 + lr)*128 + seg);
#pragma unroll
      for (int c = 0; c < 4; ++c)
        bx[c] = *(const short8*)(xsb + (wy*64 + c*16 + lr)*128 + seg);
#pragma unroll
      for (int r = 0; r < 4; ++r)
#pragma unroll
        for (int c = 0; c < 4; ++c)
          acc[r][c] = __builtin_amdgcn_mfma_f32_16x16x32_bf16(aw[r], bx[c], acc[r][c], 0, 0, 0);
    }
    __syncthreads();                   // drains prefetch; orders reads vs overwrite
  }
  // acc[r][c]: chan = ct*128 + wx*64 + r*16 + lq*4 + reg ; pix = nt*128 + wy*64 + c*16 + lr

  const int ch8 = (tid & 15) * 8;      // store-phase chan offset within 128
  float s_mul = 1.f;
  f32x4 be0 = (f32x4){0.f,0.f,0.f,0.f}, be1 = be0;
  if constexpr (EPI == 1 || EPI == 2 || EPI == 3 || EPI == 5){
    be0 = *(const f32x4*)&bias[ct*128 + ch8];
    be1 = *(const f32x4*)&bias[ct*128 + ch8 + 4];
  }
  if constexpr (FOLD && EPI != 4){
    const float mean = stIn[b*2]   * (1.f/NE_PB);
    const float m2   = stIn[b*2+1] * (1.f/NE_PB);
    const float inv  = rsqrtf(m2 - mean*mean + 1e-5f);
    s_mul = inv;
    const float muinv = mean * inv;
    const float* up = &uv[(size_t)(ct*128 + ch8)*2];
#pragma unroll
    for (int k = 0; k < 4; ++k){
      f32x2 p0 = *(const f32x2*)&up[k*2];       // chan ch8+k   : (u,v)
      f32x2 p1 = *(const f32x2*)&up[8 + k*2];   // chan ch8+4+k : (u,v)
      be0[k] += p0.y - muinv*p0.x;
      be1[k] += p1.y - muinv*p1.x;
    }
  }

  float sm = 0.f, ss = 0.f;

  if constexpr (EPI != 4){
    // 2 passes over pixel halves; CT[pixL 0..63][chan 0..127], stride 132
#pragma unroll
    for (int p = 0; p < 2; ++p){
      __syncthreads();
      if (wy == p){
#pragma unroll
        for (int r = 0; r < 4; ++r)
#pragma unroll
          for (int c = 0; c < 4; ++c)
            *(f32x4*)&CT[(c*16 + lr)*132 + wx*64 + r*16 + lq*4] = acc[r][c];
      }
      __syncthreads();
#pragma unroll
      for (int it = 0; it < 4; ++it){
        const int pixL = it*16 + (tid >> 4);
        f32x4 v0 = *(const f32x4*)&CT[pixL*132 + ch8];
        f32x4 v1 = *(const f32x4*)&CT[pixL*132 + ch8 + 4];
        if constexpr (EPI != 0){
          v0.x = v0.x*s_mul + be0.x; v0.y = v0.y*s_mul + be0.y;
          v0.z = v0.z*s_mul + be0.z; v0.w = v0.w*s_mul + be0.w;
          v1.x = v1.x*s_mul + be1.x; v1.y = v1.y*s_mul + be1.y;
          v1.z = v1.z*s_mul + be1.z; v1.w = v1.w*s_mul + be1.w;
        }
        int pixg = nt*128 + p*64 + pixL;
        if constexpr (EPI == 5) pixg = pi2pix(pixg);
        const size_t rowb = (size_t)b*NPIX + pixg;
        if constexpr (EPI == 0){
          short8 o;
          o[0]=f2b(v0.x); o[1]=f2b(v0.y); o[2]=f2b(v0.z); o[3]=f2b(v0.w);
          o[4]=f2b(v1.x); o[5]=f2b(v1.y); o[6]=f2b(v1.z); o[7]=f2b(v1.w);
          *(short8*)&P[rowb*256 + ct*128 + ch8] = o;
          sm += v0.x+v0.y+v0.z+v0.w + v1.x+v1.y+v1.z+v1.w;
          ss += v0.x*v0.x+v0.y*v0.y+v0.z*v0.z+v0.w*v0.w
              + v1.x*v1.x+v1.y*v1.y+v1.z*v1.z+v1.w*v1.w;
        } else if constexpr (EPI == 2 || EPI == 5){
          short* pp = &P[rowb*256 + ct*128 + ch8];
          short8 old = *(const short8*)pp;
          float n0 = b2f(old[0])+v0.x, n1 = b2f(old[1])+v0.y;
          float n2 = b2f(old[2])+v0.z, n3 = b2f(old[3])+v0.w;
          float n4 = b2f(old[4])+v1.x, n5 = b2f(old[5])+v1.y;
          float n6 = b2f(old[6])+v1.z, n7 = b2f(old[7])+v1.w;
          short8 o;
          o[0]=f2b(n0); o[1]=f2b(n1); o[2]=f2b(n2); o[3]=f2b(n3);
          o[4]=f2b(n4); o[5]=f2b(n5); o[6]=f2b(n6); o[7]=f2b(n7);
          *(short8*)pp = o;
          sm += n0+n1+n2+n3+n4+n5+n6+n7;
          ss += n0*n0+n1*n1+n2*n2+n3*n3+n4*n4+n5*n5+n6*n6+n7*n7;
        } else if constexpr (EPI == 1){
          short8 o;
          o[0]=f2b(v0.x); o[1]=f2b(v0.y); o[2]=f2b(v0.z); o[3]=f2b(v0.w);
          o[4]=f2b(v1.x); o[5]=f2b(v1.y); o[6]=f2b(v1.z); o[7]=f2b(v1.w);
          *(short8*)&Obf[rowb*(size_t)M + ct*128 + ch8] = o;
        } else {  // EPI == 3
          short8 o;
          o[0]=f2b(silu_f(v0.x)); o[1]=f2b(silu_f(v0.y));
          o[2]=f2b(silu_f(v0.z)); o[3]=f2b(silu_f(v0.w));
          o[4]=f2b(silu_f(v1.x)); o[5]=f2b(silu_f(v1.y));
          o[6]=f2b(silu_f(v1.z)); o[7]=f2b(silu_f(v1.w));
          *(short8*)&Obf[rowb*(size_t)M + ct*128 + ch8] = o;
        }
      }
    }
    if constexpr (EPI == 0 || EPI == 2 || EPI == 5){
#pragma unroll
      for (int o = 32; o > 0; o >>= 1){ sm += __shfl_down(sm, o); ss += __shfl_down(ss, o); }
      if (ln == 0){ red[wv*2] = sm; red[wv*2+1] = ss; }
      __syncthreads();
      if (tid == 0){
        atomicAdd(&st[b*2+0], red[0]+red[2]+red[4]+red[6]);
        atomicAdd(&st[b*2+1], red[1]+red[3]+red[5]+red[7]);
      }
    }
  } else {
    // EPI 4: BN (+FOLD) -> f32 NCHW; 2 passes over chan halves; CT[chanL][pix]
    float muinv4 = 0.f;
    if constexpr (FOLD){
      const float mean = stIn[b*2]   * (1.f/NE_PB);
      const float m2   = stIn[b*2+1] * (1.f/NE_PB);
      const float inv  = rsqrtf(m2 - mean*mean + 1e-5f);
      s_mul = inv;
      muinv4 = mean * inv;
    }
#pragma unroll
    for (int p = 0; p < 2; ++p){
      __syncthreads();
      if (wx == p){
#pragma unroll
        for (int r = 0; r < 4; ++r)
#pragma unroll
          for (int c = 0; c < 4; ++c){
            const int pixL = wy*64 + c*16 + lr;
#pragma unroll
            for (int j = 0; j < 4; ++j)
              CT[(r*16 + lq*4 + j)*132 + pixL] = acc[r][c][j];
          }
      }
      __syncthreads();
#pragma unroll
      for (int it = 0; it < 8; ++it){
        const int idx = it*256 + tid;
        const int chL = idx >> 5, pq = (idx & 31)*4;
        const int chan = ct*128 + p*64 + chL;
        f32x4 v = *(const f32x4*)&CT[chL*132 + pq];
        const float sc = bng[chan] * rsqrtf(bnv[chan] + 1e-5f);
        const float mu = bnm[chan], bb = bnb[chan];
        float A = sc, Bc = -mu*sc + bb;
        if constexpr (FOLD){
          f32x2 uvp = *(const f32x2*)&uv[(size_t)chan*2];
          A = s_mul * sc;
          Bc = ((uvp.y - muinv4*uvp.x) - mu)*sc + bb;
        }
        f32x4 o;
        o.x = v.x*A + Bc; o.y = v.y*A + Bc;
        o.z = v.z*A + Bc; o.w = v.w*A + Bc;
        *(f32x4*)&Of32[((size_t)(b*C_ + chan))*NPIX + (size_t)nt*128 + pq] = o;
      }
    }
  }
}

// ---------- q = inv*(Wq.g . p) + (qb + vq - inv*mu*uq)  (gathered pi rows) ----------
__global__ void q_k(const short* __restrict__ P, const float* __restrict__ Wq,
                    const float* __restrict__ Gg, const float* __restrict__ Qb,
                    const float* __restrict__ uv, const float* __restrict__ stIn,
                    float* __restrict__ Q){
  const int lane = threadIdx.x & 63;
  const int pix = (blockIdx.x*256 + threadIdx.x) >> 6;   // b*4096 + pi
  const int b = pix >> 12, pi = pix & 4095;
  const int prow = pi2pix(pi);
  short4v u4 = *(const short4v*)&P[((size_t)b*NPIX + prow)*256 + lane*4];
  f32x4  w4 = *(const f32x4*)&Wq[lane*4];
  f32x4  g4 = *(const f32x4*)&Gg[lane*4];
  float s = b2f(u4.x)*w4.x*g4.x + b2f(u4.y)*w4.y*g4.y
          + b2f(u4.z)*w4.z*g4.z + b2f(u4.w)*w4.w*g4.w;
#pragma unroll
  for (int o = 32; o > 0; o >>= 1) s += __shfl_down(s, o);
  if (lane == 0){
    const float mean = stIn[b*2]   * (1.f/NE_PB);
    const float m2   = stIn[b*2+1] * (1.f/NE_PB);
    const float inv  = rsqrtf(m2 - mean*mean + 1e-5f);
    Q[pix] = inv*s + Qb[0] + uv[1] - inv*mean*uv[0];
  }
}

// ---------- softmax over 1024 contiguous pi-pixels; also zeroes ctx accum ----------
__global__ void softmax_k(const float* __restrict__ Q, float* __restrict__ S,
                          float* __restrict__ CT){
  const int bp = blockIdx.x;
  const int t = threadIdx.x;
  CT[bp*256 + t] = 0.f;
  float vals[4];
  float mx = -1e30f;
#pragma unroll
  for (int j = 0; j < 4; ++j){
    vals[j] = Q[bp*1024 + t + j*256];
    mx = fmaxf(mx, vals[j]);
  }
  __shared__ float red[4];
  const int lane = t & 63, wv = t >> 6;
#pragma unroll
  for (int o = 32; o > 0; o >>= 1) mx = fmaxf(mx, __shfl_down(mx, o));
  if (lane == 0) red[wv] = mx;
  __syncthreads();
  mx = fmaxf(fmaxf(red[0], red[1]), fmaxf(red[2], red[3]));
  __syncthreads();
  float sum = 0.f;
#pragma unroll
  for (int j = 0; j < 4; ++j){ vals[j] = expf(vals[j] - mx); sum += vals[j]; }
#pragma unroll
  for (int o = 32; o > 0; o >>= 1) sum += __shfl_down(sum, o);
  if (lane == 0) red[wv] = sum;
  __syncthreads();
  sum = red[0] + red[1] + red[2] + red[3];
  const float r = 1.f / sum;
#pragma unroll
  for (int j = 0; j < 4; ++j) S[bp*1024 + t + j*256] = vals[j]*r;
}

// ---------- ctx[bp][c] = sum_n k[bp*1024+n][c] * s[bp][n]  (coalesced, atomics) ----------
__global__ void ctx_k(const short* __restrict__ KV, const float* __restrict__ S,
                      float* __restrict__ CT){
  const int bp = blockIdx.x, ch = blockIdx.y;
  const int ln = threadIdx.x & 63, wv = threadIdx.x >> 6;
  const int j0 = ch*256 + wv*64;
  f32x4 acc = (f32x4){0.f,0.f,0.f,0.f};
  for (int jj = 0; jj < 64; jj += 4){
    f32x4 s4 = *(const f32x4*)&S[bp*1024 + j0 + jj];
#pragma unroll
    for (int u = 0; u < 4; ++u){
      short4v kv = *(const short4v*)&KV[((size_t)bp*1024 + j0 + jj + u)*512 + ln*4];
      const float s = s4[u];
      acc.x += b2f(kv.x)*s; acc.y += b2f(kv.y)*s;
      acc.z += b2f(kv.z)*s; acc.w += b2f(kv.w)*s;
    }
  }
  atomicAdd(&CT[bp*256 + ln*4 + 0], acc.x);
  atomicAdd(&CT[bp*256 + ln*4 + 1], acc.y);
  atomicAdd(&CT[bp*256 + ln*4 + 2], acc.z);
  atomicAdd(&CT[bp*256 + ln*4 + 3], acc.w);
}

// ---------- attn input: relu(v) * ctx[parity]  (all pi-ordered) ----------
__global__ void attn_in_k(const short* __restrict__ KV, const float* __restrict__ CT,
                          short* __restrict__ O){
  const size_t vid = (size_t)blockIdx.x*256 + threadIdx.x;
  const int c4 = (int)(vid & 63);
  const size_t r = vid >> 6;
  const int bp = (int)(r >> 10);
  short4v v4 = *(const short4v*)&KV[r*512 + 256 + c4*4];
  f32x4  cx = *(const f32x4*)&CT[bp*256 + c4*4];
  short4v o;
  o.x = f2b(fmaxf(b2f(v4.x), 0.f)*cx.x);
  o.y = f2b(fmaxf(b2f(v4.y), 0.f)*cx.y);
  o.z = f2b(fmaxf(b2f(v4.z), 0.f)*cx.z);
  o.w = f2b(fmaxf(b2f(v4.w), 0.f)*cx.w);
  *(short4v*)&O[r*256 + c4*4] = o;
}

extern "C" void kernel_launch(void* const* d_in, const int* in_sizes, int n_in,
                              void* d_out, int out_size, void* d_ws, size_t ws_size,
                              hipStream_t stream){
  const float* x      = (const float*)d_in[0];
  const float* dw_w   = (const float*)d_in[1];
  const float* dw_g   = (const float*)d_in[2];
  const float* dw_b   = (const float*)d_in[3];
  const float* dw_m   = (const float*)d_in[4];
  const float* dw_v   = (const float*)d_in[5];
  const float* pw_w   = (const float*)d_in[6];
  const float* gn1_g  = (const float*)d_in[7];
  const float* gn1_b  = (const float*)d_in[8];
  const float* qkv_w  = (const float*)d_in[9];
  const float* qkv_b  = (const float*)d_in[10];
  const float* out_w  = (const float*)d_in[11];
  const float* out_b  = (const float*)d_in[12];
  const float* gn2_g  = (const float*)d_in[13];
  const float* gn2_b  = (const float*)d_in[14];
  const float* ffn1_w = (const float*)d_in[15];
  const float* ffn1_b = (const float*)d_in[16];
  const float* ffn2_w = (const float*)d_in[17];
  const float* ffn2_b = (const float*)d_in[18];
  const float* gnf_g  = (const float*)d_in[19];
  const float* gnf_b  = (const float*)d_in[20];
  const float* proj_w = (const float*)d_in[21];
  const float* pbn_g  = (const float*)d_in[22];
  const float* pbn_b  = (const float*)d_in[23];
  const float* pbn_m  = (const float*)d_in[24];
  const float* pbn_v  = (const float*)d_in[25];
  float* out = (float*)d_out;

  uint8_t* w8 = (uint8_t*)d_ws;
  short* P     = (short*)(w8);                  // bf16 residual, 32 MiB
  short* bufA  = (short*)(w8 + 33554432);       // bf16 (B,4096,256), 32 MiB
  short* bufB  = (short*)(w8 + 67108864);       // bf16 (B,4096,512), 64 MiB
  short* wbase = (short*)(w8 + 134217728);      // all weights bf16, contiguous
  short* w_pw  = wbase;
  short* w_qkv = wbase + 65536;
  short* w_out = wbase + 328192;
  short* w_f1  = wbase + 459264;
  short* w_f2  = wbase + 721408;
  short* w_pj  = wbase + 983552;
  float* qbuf  = (float*)(w8 + 136315904);      // (B*4096)
  float* scor  = (float*)(w8 + 136578048);      // (64,1024)
  float* ctxs  = (float*)(w8 + 136840192);      // (64,256)
  float* stats = (float*)(w8 + 136905728);      // 5 sites x 16 x 2 (640 B)
  float* uvb   = (float*)(w8 + 136906368);      // 2306 x 2 f32 (18448 B)

  cvt6_k<<<4098, 256, 0, stream>>>(pw_w, qkv_w, out_w, ffn1_w, ffn2_w, proj_w,
                                   gn1_g, gn2_g, gnf_g, wbase, stats);
  fold_k<<<2306, 64, 0, stream>>>(qkv_w, ffn1_w, proj_w,
                                  gn1_g, gn1_b, gn2_g, gn2_b, gnf_g, gnf_b, uvb);

  dwconv_k<<<dim3(256,16), 256, 0, stream>>>(x, dw_w, dw_g, dw_b, dw_m, dw_v, bufB);
  transpose_k<<<dim3(64,4,16), 256, 0, stream>>>(bufB, bufA);

  // pw conv -> P (stats site 0 = gn1 layer 0)
  gemm_k<0,256,0,0><<<dim3(32,2,16), 256, 0, stream>>>(w_pw, bufA, 256, nullptr, P,
      nullptr, nullptr, nullptr, nullptr, nullptr, nullptr, stats + 0,
      nullptr, nullptr);

  for (int i = 0; i < 2; ++i){
    float* st1 = stats + (i == 0 ? 0 : 2)*32;            // gn1 site
    q_k<<<16384, 256, 0, stream>>>(P, qkv_w + (size_t)i*513*256, gn1_g + i*256,
        qkv_b + i*513, uvb + (size_t)(i*513)*2, st1, qbuf);
    gemm_k<1,256,1,1><<<dim3(32,4,16), 256, 0, stream>>>(w_qkv + (i*513+1)*256, P, 512,
        qkv_b + i*513 + 1, nullptr, bufB, nullptr, nullptr, nullptr, nullptr, nullptr,
        nullptr, uvb + (size_t)(i*513+1)*2, st1);
    softmax_k<<<64, 256, 0, stream>>>(qbuf, scor, ctxs);
    ctx_k<<<dim3(64,4), 256, 0, stream>>>(bufB, scor, ctxs);
    attn_in_k<<<16384, 256, 0, stream>>>(bufB, ctxs, bufA);
    // out proj: P += (unpermute), stats -> gn2 site
    gemm_k<5,256,0,0><<<dim3(32,2,16), 256, 0, stream>>>(w_out + i*65536, bufA, 256,
        out_b + i*256, P, nullptr, nullptr, nullptr, nullptr, nullptr, nullptr,
        stats + (i == 0 ? 1 : 3)*32, nullptr, nullptr);
    float* st2 = stats + (i == 0 ? 1 : 3)*32;
    gemm_k<3,256,1,0><<<dim3(32,4,16), 256, 0, stream>>>(w_f1 + i*131072, P, 512,
        ffn1_b + i*512, nullptr, bufB, nullptr, nullptr, nullptr, nullptr, nullptr,
        nullptr, uvb + (size_t)(1026 + i*512)*2, st2);
    // ffn2: P += , stats -> next gn1 site (i=0) or gnf site (i=1)
    gemm_k<2,512,0,0><<<dim3(32,2,16), 256, 0, stream>>>(w_f2 + i*131072, bufB, 256,
        ffn2_b + i*256, P, nullptr, nullptr, nullptr, nullptr, nullptr, nullptr,
        stats + (i == 0 ? 2 : 4)*32, nullptr, nullptr);
  }

  gemm_k<4,256,1,0><<<dim3(32,2,16), 256, 0, stream>>>(w_pj, P, 256, nullptr,
      nullptr, nullptr, out, pbn_g, pbn_b, pbn_m, pbn_v, nullptr,
      uvb + (size_t)2050*2, stats + 4*32);

  (void)in_sizes; (void)n_in; (void)out_size; (void)ws_size;
}

// Round 6
// 646.467 us; speedup vs baseline: 1.0312x; 1.0312x over previous
//
#include <hip/hip_runtime.h>
#include <hip/hip_bf16.h>
#include <stdint.h>

// MobileViTBlockV2: B=16, C=256, H=W=64, D=256, F=512, L=2, patch 2x2.
// R10: base = R8 (verified 623.8us; R9's double-buffer regressed and is
// reverted). Change: FOLD constants (inv, bias+v-mu*inv*u) precomputed per
// (site,batch,chan) by tiny beta0_k/beta4_k kernels; GEMM epilogue just loads
// beta like a bias + one scalar alpha[b]. Rationale: R8's in-kernel fold
// pushed VGPR 64->72; with 64 AGPR acc on gfx950's unified file that crossed
// the 128-reg occupancy cliff (4->2 waves/SIMD, occ 30->19%). launch_bounds
// (256,4) pins total regs <=128.

#define B_    16
#define C_    256
#define D_    256
#define NPIX  4096
#define NE_PB 1048576   // D_*NPIX elements per batch for GN

typedef __attribute__((ext_vector_type(8))) short  short8;
typedef __attribute__((ext_vector_type(4))) short  short4v;
typedef __attribute__((ext_vector_type(4))) float  f32x4;
typedef __attribute__((ext_vector_type(2))) float  f32x2;

__device__ __forceinline__ float b2f(short s){
  return __uint_as_float(((unsigned)(unsigned short)s) << 16);
}
__device__ __forceinline__ short f2b(float f){
  unsigned u = __float_as_uint(f);
  return (short)((u + 0x7fffu + ((u >> 16) & 1u)) >> 16);  // RNE
}
__device__ __forceinline__ float silu_f(float x){ return x / (1.f + expf(-x)); }

__device__ __forceinline__ void gld16(const short* g, short* l){
  __builtin_amdgcn_global_load_lds(
      (const __attribute__((address_space(1))) void*)g,
      (__attribute__((address_space(3))) void*)l, 16, 0, 0);
}

// pi (parity-permuted) -> pixel: pi = parity*1024 + (h/2)*32 + (w/2)
__device__ __forceinline__ int pi2pix(int n){
  int p = n >> 10, idx = n & 1023;
  int h = ((idx >> 5) << 1) | (p >> 1);
  int w = ((idx & 31) << 1) | (p & 1);
  return h*64 + w;
}

// ---------- all weight casts (g-scaled at fold sites) + stats zero ----------
__global__ void cvt6_k(const float* __restrict__ s0, const float* __restrict__ s1,
                       const float* __restrict__ s2, const float* __restrict__ s3,
                       const float* __restrict__ s4, const float* __restrict__ s5,
                       const float* __restrict__ g1, const float* __restrict__ g2,
                       const float* __restrict__ gf,
                       short* __restrict__ dst, float* __restrict__ stats){
  const int i = blockIdx.x*256 + threadIdx.x;
  if (blockIdx.x == 0 && threadIdx.x < 160) stats[threadIdx.x] = 0.f;
  if (i >= 1049088) return;
  float v;
  if      (i <  65536){ v = s0[i]; }                                    // pw
  else if (i < 328192){ int j = i -  65536;                             // qkv (fold gn1)
                        v = s1[j] * g1[(j/131328)*256 + (j & 255)]; }
  else if (i < 459264){ v = s2[i - 328192]; }                           // out
  else if (i < 721408){ int j = i - 459264;                             // ffn1 (fold gn2)
                        v = s3[j] * g2[(j >> 17)*256 + (j & 255)]; }
  else if (i < 983552){ v = s4[i - 721408]; }                           // ffn2
  else               { int j = i - 983552;                              // proj (fold gnf)
                        v = s5[j] * gf[j & 255]; }
  dst[i] = f2b(v);
}

// ---------- per-site u = W.g, v = W.b  (one wave per output row) ----------
// rows: [0,1026) qkv L0/L1 (513 each, row0=q) ; [1026,2050) ffn1 L0/L1 ;
// [2050,2306) proj. uv[row*2] = u, uv[row*2+1] = v.
__global__ void fold_k(const float* __restrict__ qkvw, const float* __restrict__ f1w,
                       const float* __restrict__ pjw,
                       const float* __restrict__ g1, const float* __restrict__ b1,
                       const float* __restrict__ g2, const float* __restrict__ b2,
                       const float* __restrict__ gf, const float* __restrict__ bf,
                       float* __restrict__ uv){
  const int row = blockIdx.x;
  const int l = threadIdx.x;
  const float* W; const float* g; const float* bb;
  if (row < 1026){ int layer = row/513, o = row - layer*513;
    W = qkvw + (size_t)(layer*513 + o)*256; g = g1 + layer*256; bb = b1 + layer*256; }
  else if (row < 2050){ int r2 = row - 1026; int layer = r2 >> 9, o = r2 & 511;
    W = f1w + (size_t)(layer*512 + o)*256; g = g2 + layer*256; bb = b2 + layer*256; }
  else { int o = row - 2050; W = pjw + (size_t)o*256; g = gf; bb = bf; }
  float u = 0.f, v = 0.f;
#pragma unroll
  for (int k = 0; k < 4; ++k){
    const int c = l + k*64;
    const float w = W[c];
    u += w * g[c]; v += w * bb[c];
  }
#pragma unroll
  for (int o = 32; o > 0; o >>= 1){ u += __shfl_down(u, o); v += __shfl_down(v, o); }
  if (l == 0){ uv[row*2] = u; uv[row*2+1] = v; }
}

// ---------- per-(b,chan) fold constants for a consumer GEMM site ----------
// beta[b*M+c] = bias[c] + v[c] - mean*inv*u[c] ; alpha[b] = inv
__global__ void beta0_k(const float* __restrict__ bias, const float* __restrict__ uv,
                        const float* __restrict__ stIn, const int M,
                        float* __restrict__ beta, float* __restrict__ alpha){
  const int b = blockIdx.y;
  const int c = blockIdx.x*256 + threadIdx.x;
  const float mean = stIn[b*2]   * (1.f/NE_PB);
  const float m2   = stIn[b*2+1] * (1.f/NE_PB);
  const float inv  = rsqrtf(m2 - mean*mean + 1e-5f);
  if (c < M){
    f32x2 p = *(const f32x2*)&uv[(size_t)c*2];
    beta[(size_t)b*M + c] = bias[c] + p.y - mean*inv*p.x;
  }
  if (c == 0 && blockIdx.x == 0) alpha[b] = inv;
}

// proj site: GN fold composed with BN -> per-(b,chan) A,B
__global__ void beta4_k(const float* __restrict__ g, const float* __restrict__ bb,
                        const float* __restrict__ m, const float* __restrict__ vr,
                        const float* __restrict__ uv, const float* __restrict__ stIn,
                        float* __restrict__ A, float* __restrict__ B){
  const int b = blockIdx.x;
  const int c = threadIdx.x;
  const float mean = stIn[b*2]   * (1.f/NE_PB);
  const float m2   = stIn[b*2+1] * (1.f/NE_PB);
  const float inv  = rsqrtf(m2 - mean*mean + 1e-5f);
  const float sc = g[c] * rsqrtf(vr[c] + 1e-5f);
  f32x2 p = *(const f32x2*)&uv[(size_t)c*2];
  A[b*256 + c] = inv*sc;
  B[b*256 + c] = (p.y - mean*inv*p.x - m[c])*sc + bb[c];
}

// ---------- dwconv3x3 + BN + SiLU: one block per (b,c) plane ----------
__global__ __launch_bounds__(256)
void dwconv_k(const float* __restrict__ X, const float* __restrict__ W,
              const float* __restrict__ G, const float* __restrict__ Bb,
              const float* __restrict__ Mn, const float* __restrict__ Vr,
              short* __restrict__ O){
  const int c = blockIdx.x, b = blockIdx.y;
  const int t = threadIdx.x;
  __shared__ float xs[66][68];
  // halo zero
  if (t < 132){ int r = (t >= 66) ? 65 : 0; int cc = (t >= 66) ? t-66 : t; xs[r][cc] = 0.f; }
  if (t < 128){ int r = 1 + (t & 63); int cc = (t >> 6) ? 65 : 0; xs[r][cc] = 0.f; }
  const float* xp = X + ((size_t)(b*C_ + c)) * NPIX;
#pragma unroll
  for (int it = 0; it < 4; ++it){
    const int idx = it*256 + t;
    const int row = idx >> 4, cq = idx & 15;
    f32x4 v = *(const f32x4*)&xp[row*64 + cq*4];
    xs[row+1][cq*4+1] = v.x; xs[row+1][cq*4+2] = v.y;
    xs[row+1][cq*4+3] = v.z; xs[row+1][cq*4+4] = v.w;
  }
  float wgt[9];
#pragma unroll
  for (int j = 0; j < 9; ++j) wgt[j] = W[c*9 + j];
  const float scale = G[c] * rsqrtf(Vr[c] + 1e-5f);
  const float mu = Mn[c], bb = Bb[c];
  __syncthreads();
  const int tr = t >> 4, tc = t & 15;
  float win[6][6];
#pragma unroll
  for (int dr = 0; dr < 6; ++dr){
    f32x4 a = *(const f32x4*)&xs[tr*4+dr][tc*4];
    f32x2 bq = *(const f32x2*)&xs[tr*4+dr][tc*4+4];
    win[dr][0] = a.x; win[dr][1] = a.y; win[dr][2] = a.z; win[dr][3] = a.w;
    win[dr][4] = bq.x; win[dr][5] = bq.y;
  }
  short* op = O + ((size_t)(b*C_ + c)) * NPIX;
#pragma unroll
  for (int jr = 0; jr < 4; ++jr){
    short4v o;
#pragma unroll
    for (int jc = 0; jc < 4; ++jc){
      float s = 0.f;
#pragma unroll
      for (int dh = 0; dh < 3; ++dh)
#pragma unroll
        for (int dw = 0; dw < 3; ++dw)
          s += win[jr+dh][jc+dw] * wgt[dh*3+dw];
      float y = (s - mu) * scale + bb;
      o[jc] = f2b(silu_f(y));
    }
    *(short4v*)&op[(tr*4+jr)*64 + tc*4] = o;
  }
}

// ---------- (b,c,s) -> (b,s,c) bf16 transpose, 64x64 tiles, vector both sides ----------
__global__ void transpose_k(const short* __restrict__ I, short* __restrict__ O){
  const int s0 = blockIdx.x*64, c0 = blockIdx.y*64, b = blockIdx.z;
  const int t = threadIdx.x;
  __shared__ short tile[64][68];   // [s_local][c_local]
  const int hi = t >> 4, lo = t & 15;
#pragma unroll
  for (int cy = 0; cy < 4; ++cy){
    const int cl = cy*16 + hi;
    short4v v = *(const short4v*)&I[((size_t)(b*C_ + c0 + cl))*NPIX + s0 + lo*4];
    tile[lo*4+0][cl] = v.x; tile[lo*4+1][cl] = v.y;
    tile[lo*4+2][cl] = v.z; tile[lo*4+3][cl] = v.w;
  }
  __syncthreads();
#pragma unroll
  for (int py = 0; py < 4; ++py){
    const int pl = py*16 + hi;
    short4v v = *(const short4v*)&tile[pl][lo*4];
    *(short4v*)&O[((size_t)(b*NPIX + s0 + pl))*C_ + c0 + lo*4] = v;
  }
}

// ---------- MFMA bf16 GEMM: D[pix][chan] = sum_k X[pix][k]*Wt[chan][k] ----------
// Tile 128 pix x 128 chan, BK=64. W is the MFMA A operand (chan on reg axis).
// EPI: 0 = P(bf16)=acc (+stats); 1 = bf16 Obf = acc+bias;
// 2 = P += acc+bias (+stats); 3 = bf16 Obf = silu(acc+bias);
// 4 = f32 NCHW Of32 = BN(acc); 5 = P += acc+bias at pi2pix(row) (+stats)
// FOLD: GN folded input — epilogue out = acc*al[b] + beta[b][chan]
//       (beta precomputed by beta0_k/beta4_k; keeps regs at the R5 profile).
// GATHER: stage X rows at pi2pix(row) (per-lane global address).
template<int EPI, int K, int FOLD, int GATHER>
__global__ __launch_bounds__(256, 4)
void gemm_k(const short* __restrict__ Wt, const short* __restrict__ X,
            const int M,
            const float* __restrict__ bias,
            short* __restrict__ P,
            short* __restrict__ Obf,
            float* __restrict__ Of32,
            const float* __restrict__ bng, const float* __restrict__ bnb,
            const float* __restrict__ bnm, const float* __restrict__ bnv,
            float* __restrict__ st,
            const float* __restrict__ al, const float* __restrict__ beta)
{
  constexpr int S = K / 64;
  const int nt = blockIdx.x;          // pixel tile (128)
  const int ct = blockIdx.y;          // chan tile (128)
  const int b  = blockIdx.z;
  const int tid = threadIdx.x;
  const int ln = tid & 63, wv = tid >> 6;
  const int wx = wv & 1;              // chan half (64)
  const int wy = wv >> 1;             // pixel half (64)
  const int lr = ln & 15, lq = ln >> 4;
  const int rl = ln >> 3, sp = ln & 7;
  const int sw = sp ^ rl;             // staged k-seg (XOR swizzle)

  __shared__ __align__(16) char smem[33824];
  short* As = (short*)smem;            // W tile: 128 chan rows x 64 k (16 KB)
  short* Xs = (short*)(smem + 16384);  // X tile: 128 pix rows x 64 k (16 KB)
  float* CT = (float*)smem;            // epilogue restage (64x132 f32)
  float* red = (float*)(smem + 33792); // 8 floats

  const short* Wp = Wt + (size_t)(ct*128)*K;
  const short* Xp = X + ((size_t)b*NPIX + (size_t)nt*128) * K;

  const short* gw[4]; const short* gx[4]; short* lw[4]; short* lx[4];
#pragma unroll
  for (int j = 0; j < 4; ++j){
    const int row = 32*wv + 8*j + rl;
    gw[j] = Wp + (size_t)row*K + sw*8;
    if constexpr (GATHER)
      gx[j] = X + ((size_t)b*NPIX + pi2pix(nt*128 + row))*K + sw*8;
    else
      gx[j] = Xp + (size_t)row*K + sw*8;
    lw[j] = As + (4*wv + j)*512;
    lx[j] = Xs + (4*wv + j)*512;
  }

  f32x4 acc[4][4];
#pragma unroll
  for (int r = 0; r < 4; ++r)
#pragma unroll
    for (int c = 0; c < 4; ++c) acc[r][c] = (f32x4){0.f,0.f,0.f,0.f};

  for (int stp = 0; stp < S; ++stp){
    if (stp) __syncthreads();
#pragma unroll
    for (int j = 0; j < 4; ++j) gld16(gw[j] + stp*64, lw[j]);
#pragma unroll
    for (int j = 0; j < 4; ++j) gld16(gx[j] + stp*64, lx[j]);
    __syncthreads();
#pragma unroll
    for (int kk = 0; kk < 2; ++kk){
      const int seg = ((kk*4 + lq) ^ (lr & 7)) * 16;   // byte offset in 128B row
      short8 aw[4], bx[4];
#pragma unroll
      for (int r = 0; r < 4; ++r)
        aw[r] = *(const short8*)((const char*)As + (wx*64 + r*16 + lr)*128 + seg);
#pragma unroll
      for (int c = 0; c < 4; ++c)
        bx[c] = *(const short8*)((const char*)Xs + (wy*64 + c*16 + lr)*128 + seg);
#pragma unroll
      for (int r = 0; r < 4; ++r)
#pragma unroll
        for (int c = 0; c < 4; ++c)
          acc[r][c] = __builtin_amdgcn_mfma_f32_16x16x32_bf16(aw[r], bx[c], acc[r][c], 0, 0, 0);
    }
  }
  // acc[r][c]: chan = ct*128 + wx*64 + r*16 + lq*4 + reg ; pix = nt*128 + wy*64 + c*16 + lr

  const int ch8 = (tid & 15) * 8;      // store-phase chan offset within 128
  float s_mul = 1.f;
  f32x4 be0 = (f32x4){0.f,0.f,0.f,0.f}, be1 = be0;
  if constexpr ((EPI == 1 || EPI == 2 || EPI == 3 || EPI == 5) && !FOLD){
    be0 = *(const f32x4*)&bias[ct*128 + ch8];
    be1 = *(const f32x4*)&bias[ct*128 + ch8 + 4];
  }
  if constexpr (FOLD && EPI != 4){
    s_mul = al[b];
    be0 = *(const f32x4*)&beta[(size_t)b*M + ct*128 + ch8];
    be1 = *(const f32x4*)&beta[(size_t)b*M + ct*128 + ch8 + 4];
  }

  float sm = 0.f, ss = 0.f;

  if constexpr (EPI != 4){
    // 2 passes over pixel halves; CT[pixL 0..63][chan 0..127], stride 132
#pragma unroll
    for (int p = 0; p < 2; ++p){
      __syncthreads();
      if (wy == p){
#pragma unroll
        for (int r = 0; r < 4; ++r)
#pragma unroll
          for (int c = 0; c < 4; ++c)
            *(f32x4*)&CT[(c*16 + lr)*132 + wx*64 + r*16 + lq*4] = acc[r][c];
      }
      __syncthreads();
#pragma unroll
      for (int it = 0; it < 4; ++it){
        const int pixL = it*16 + (tid >> 4);
        f32x4 v0 = *(const f32x4*)&CT[pixL*132 + ch8];
        f32x4 v1 = *(const f32x4*)&CT[pixL*132 + ch8 + 4];
        if constexpr (EPI != 0){
          if constexpr (FOLD){
            v0.x = v0.x*s_mul + be0.x; v0.y = v0.y*s_mul + be0.y;
            v0.z = v0.z*s_mul + be0.z; v0.w = v0.w*s_mul + be0.w;
            v1.x = v1.x*s_mul + be1.x; v1.y = v1.y*s_mul + be1.y;
            v1.z = v1.z*s_mul + be1.z; v1.w = v1.w*s_mul + be1.w;
          } else {
            v0.x += be0.x; v0.y += be0.y; v0.z += be0.z; v0.w += be0.w;
            v1.x += be1.x; v1.y += be1.y; v1.z += be1.z; v1.w += be1.w;
          }
        }
        int pixg = nt*128 + p*64 + pixL;
        if constexpr (EPI == 5) pixg = pi2pix(pixg);
        const size_t rowb = (size_t)b*NPIX + pixg;
        if constexpr (EPI == 0){
          short8 o;
          o[0]=f2b(v0.x); o[1]=f2b(v0.y); o[2]=f2b(v0.z); o[3]=f2b(v0.w);
          o[4]=f2b(v1.x); o[5]=f2b(v1.y); o[6]=f2b(v1.z); o[7]=f2b(v1.w);
          *(short8*)&P[rowb*256 + ct*128 + ch8] = o;
          sm += v0.x+v0.y+v0.z+v0.w + v1.x+v1.y+v1.z+v1.w;
          ss += v0.x*v0.x+v0.y*v0.y+v0.z*v0.z+v0.w*v0.w
              + v1.x*v1.x+v1.y*v1.y+v1.z*v1.z+v1.w*v1.w;
        } else if constexpr (EPI == 2 || EPI == 5){
          short* pp = &P[rowb*256 + ct*128 + ch8];
          short8 old = *(const short8*)pp;
          float n0 = b2f(old[0])+v0.x, n1 = b2f(old[1])+v0.y;
          float n2 = b2f(old[2])+v0.z, n3 = b2f(old[3])+v0.w;
          float n4 = b2f(old[4])+v1.x, n5 = b2f(old[5])+v1.y;
          float n6 = b2f(old[6])+v1.z, n7 = b2f(old[7])+v1.w;
          short8 o;
          o[0]=f2b(n0); o[1]=f2b(n1); o[2]=f2b(n2); o[3]=f2b(n3);
          o[4]=f2b(n4); o[5]=f2b(n5); o[6]=f2b(n6); o[7]=f2b(n7);
          *(short8*)pp = o;
          sm += n0+n1+n2+n3+n4+n5+n6+n7;
          ss += n0*n0+n1*n1+n2*n2+n3*n3+n4*n4+n5*n5+n6*n6+n7*n7;
        } else if constexpr (EPI == 1){
          short8 o;
          o[0]=f2b(v0.x); o[1]=f2b(v0.y); o[2]=f2b(v0.z); o[3]=f2b(v0.w);
          o[4]=f2b(v1.x); o[5]=f2b(v1.y); o[6]=f2b(v1.z); o[7]=f2b(v1.w);
          *(short8*)&Obf[rowb*(size_t)M + ct*128 + ch8] = o;
        } else {  // EPI == 3
          short8 o;
          o[0]=f2b(silu_f(v0.x)); o[1]=f2b(silu_f(v0.y));
          o[2]=f2b(silu_f(v0.z)); o[3]=f2b(silu_f(v0.w));
          o[4]=f2b(silu_f(v1.x)); o[5]=f2b(silu_f(v1.y));
          o[6]=f2b(silu_f(v1.z)); o[7]=f2b(silu_f(v1.w));
          *(short8*)&Obf[rowb*(size_t)M + ct*128 + ch8] = o;
        }
      }
    }
    if constexpr (EPI == 0 || EPI == 2 || EPI == 5){
#pragma unroll
      for (int o = 32; o > 0; o >>= 1){ sm += __shfl_down(sm, o); ss += __shfl_down(ss, o); }
      if (ln == 0){ red[wv*2] = sm; red[wv*2+1] = ss; }
      __syncthreads();
      if (tid == 0){
        atomicAdd(&st[b*2+0], red[0]+red[2]+red[4]+red[6]);
        atomicAdd(&st[b*2+1], red[1]+red[3]+red[5]+red[7]);
      }
    }
  } else {
    // EPI 4: (folded GN+)BN -> f32 NCHW; 2 passes over chan halves; CT[chanL][pix]
#pragma unroll
    for (int p = 0; p < 2; ++p){
      __syncthreads();
      if (wx == p){
#pragma unroll
        for (int r = 0; r < 4; ++r)
#pragma unroll
          for (int c = 0; c < 4; ++c){
            const int pixL = wy*64 + c*16 + lr;
#pragma unroll
            for (int j = 0; j < 4; ++j)
              CT[(r*16 + lq*4 + j)*132 + pixL] = acc[r][c][j];
          }
      }
      __syncthreads();
#pragma unroll
      for (int it = 0; it < 8; ++it){
        const int idx = it*256 + tid;
        const int chL = idx >> 5, pq = (idx & 31)*4;
        const int chan = ct*128 + p*64 + chL;
        f32x4 v = *(const f32x4*)&CT[chL*132 + pq];
        float A, Bc;
        if constexpr (FOLD){
          A  = al[b*256 + chan];
          Bc = beta[b*256 + chan];
        } else {
          const float sc = bng[chan] * rsqrtf(bnv[chan] + 1e-5f);
          A = sc; Bc = -bnm[chan]*sc + bnb[chan];
        }
        f32x4 o;
        o.x = v.x*A + Bc; o.y = v.y*A + Bc;
        o.z = v.z*A + Bc; o.w = v.w*A + Bc;
        *(f32x4*)&Of32[((size_t)(b*C_ + chan))*NPIX + (size_t)nt*128 + pq] = o;
      }
    }
  }
}

// ---------- q = inv*(Wq.g . p) + (qb + vq - inv*mu*uq)  (gathered pi rows) ----------
__global__ void q_k(const short* __restrict__ P, const float* __restrict__ Wq,
                    const float* __restrict__ Gg, const float* __restrict__ Qb,
                    const float* __restrict__ uv, const float* __restrict__ stIn,
                    float* __restrict__ Q){
  const int lane = threadIdx.x & 63;
  const int pix = (blockIdx.x*256 + threadIdx.x) >> 6;   // b*4096 + pi
  const int b = pix >> 12, pi = pix & 4095;
  const int prow = pi2pix(pi);
  short4v u4 = *(const short4v*)&P[((size_t)b*NPIX + prow)*256 + lane*4];
  f32x4  w4 = *(const f32x4*)&Wq[lane*4];
  f32x4  g4 = *(const f32x4*)&Gg[lane*4];
  float s = b2f(u4.x)*w4.x*g4.x + b2f(u4.y)*w4.y*g4.y
          + b2f(u4.z)*w4.z*g4.z + b2f(u4.w)*w4.w*g4.w;
#pragma unroll
  for (int o = 32; o > 0; o >>= 1) s += __shfl_down(s, o);
  if (lane == 0){
    const float mean = stIn[b*2]   * (1.f/NE_PB);
    const float m2   = stIn[b*2+1] * (1.f/NE_PB);
    const float inv  = rsqrtf(m2 - mean*mean + 1e-5f);
    Q[pix] = inv*s + Qb[0] + uv[1] - inv*mean*uv[0];
  }
}

// ---------- softmax over 1024 contiguous pi-pixels; also zeroes ctx accum ----------
__global__ void softmax_k(const float* __restrict__ Q, float* __restrict__ S,
                          float* __restrict__ CT){
  const int bp = blockIdx.x;
  const int t = threadIdx.x;
  CT[bp*256 + t] = 0.f;
  float vals[4];
  float mx = -1e30f;
#pragma unroll
  for (int j = 0; j < 4; ++j){
    vals[j] = Q[bp*1024 + t + j*256];
    mx = fmaxf(mx, vals[j]);
  }
  __shared__ float red[4];
  const int lane = t & 63, wv = t >> 6;
#pragma unroll
  for (int o = 32; o > 0; o >>= 1) mx = fmaxf(mx, __shfl_down(mx, o));
  if (lane == 0) red[wv] = mx;
  __syncthreads();
  mx = fmaxf(fmaxf(red[0], red[1]), fmaxf(red[2], red[3]));
  __syncthreads();
  float sum = 0.f;
#pragma unroll
  for (int j = 0; j < 4; ++j){ vals[j] = expf(vals[j] - mx); sum += vals[j]; }
#pragma unroll
  for (int o = 32; o > 0; o >>= 1) sum += __shfl_down(sum, o);
  if (lane == 0) red[wv] = sum;
  __syncthreads();
  sum = red[0] + red[1] + red[2] + red[3];
  const float r = 1.f / sum;
#pragma unroll
  for (int j = 0; j < 4; ++j) S[bp*1024 + t + j*256] = vals[j]*r;
}

// ---------- ctx[bp][c] = sum_n k[bp*1024+n][c] * s[bp][n]  (coalesced, atomics) ----------
__global__ void ctx_k(const short* __restrict__ KV, const float* __restrict__ S,
                      float* __restrict__ CT){
  const int bp = blockIdx.x, ch = blockIdx.y;
  const int ln = threadIdx.x & 63, wv = threadIdx.x >> 6;
  const int j0 = ch*256 + wv*64;
  f32x4 acc = (f32x4){0.f,0.f,0.f,0.f};
  for (int jj = 0; jj < 64; jj += 4){
    f32x4 s4 = *(const f32x4*)&S[bp*1024 + j0 + jj];
#pragma unroll
    for (int u = 0; u < 4; ++u){
      short4v kv = *(const short4v*)&KV[((size_t)bp*1024 + j0 + jj + u)*512 + ln*4];
      const float s = s4[u];
      acc.x += b2f(kv.x)*s; acc.y += b2f(kv.y)*s;
      acc.z += b2f(kv.z)*s; acc.w += b2f(kv.w)*s;
    }
  }
  atomicAdd(&CT[bp*256 + ln*4 + 0], acc.x);
  atomicAdd(&CT[bp*256 + ln*4 + 1], acc.y);
  atomicAdd(&CT[bp*256 + ln*4 + 2], acc.z);
  atomicAdd(&CT[bp*256 + ln*4 + 3], acc.w);
}

// ---------- attn input: relu(v) * ctx[parity]  (all pi-ordered) ----------
__global__ void attn_in_k(const short* __restrict__ KV, const float* __restrict__ CT,
                          short* __restrict__ O){
  const size_t vid = (size_t)blockIdx.x*256 + threadIdx.x;
  const int c4 = (int)(vid & 63);
  const size_t r = vid >> 6;
  const int bp = (int)(r >> 10);
  short4v v4 = *(const short4v*)&KV[r*512 + 256 + c4*4];
  f32x4  cx = *(const f32x4*)&CT[bp*256 + c4*4];
  short4v o;
  o.x = f2b(fmaxf(b2f(v4.x), 0.f)*cx.x);
  o.y = f2b(fmaxf(b2f(v4.y), 0.f)*cx.y);
  o.z = f2b(fmaxf(b2f(v4.z), 0.f)*cx.z);
  o.w = f2b(fmaxf(b2f(v4.w), 0.f)*cx.w);
  *(short4v*)&O[r*256 + c4*4] = o;
}

extern "C" void kernel_launch(void* const* d_in, const int* in_sizes, int n_in,
                              void* d_out, int out_size, void* d_ws, size_t ws_size,
                              hipStream_t stream){
  const float* x      = (const float*)d_in[0];
  const float* dw_w   = (const float*)d_in[1];
  const float* dw_g   = (const float*)d_in[2];
  const float* dw_b   = (const float*)d_in[3];
  const float* dw_m   = (const float*)d_in[4];
  const float* dw_v   = (const float*)d_in[5];
  const float* pw_w   = (const float*)d_in[6];
  const float* gn1_g  = (const float*)d_in[7];
  const float* gn1_b  = (const float*)d_in[8];
  const float* qkv_w  = (const float*)d_in[9];
  const float* qkv_b  = (const float*)d_in[10];
  const float* out_w  = (const float*)d_in[11];
  const float* out_b  = (const float*)d_in[12];
  const float* gn2_g  = (const float*)d_in[13];
  const float* gn2_b  = (const float*)d_in[14];
  const float* ffn1_w = (const float*)d_in[15];
  const float* ffn1_b = (const float*)d_in[16];
  const float* ffn2_w = (const float*)d_in[17];
  const float* ffn2_b = (const float*)d_in[18];
  const float* gnf_g  = (const float*)d_in[19];
  const float* gnf_b  = (const float*)d_in[20];
  const float* proj_w = (const float*)d_in[21];
  const float* pbn_g  = (const float*)d_in[22];
  const float* pbn_b  = (const float*)d_in[23];
  const float* pbn_m  = (const float*)d_in[24];
  const float* pbn_v  = (const float*)d_in[25];
  float* out = (float*)d_out;

  uint8_t* w8 = (uint8_t*)d_ws;
  short* P     = (short*)(w8);                  // bf16 residual, 32 MiB
  short* bufA  = (short*)(w8 + 33554432);       // bf16 (B,4096,256), 32 MiB
  short* bufB  = (short*)(w8 + 67108864);       // bf16 (B,4096,512), 64 MiB
  short* wbase = (short*)(w8 + 134217728);      // all weights bf16, contiguous
  short* w_pw  = wbase;
  short* w_qkv = wbase + 65536;
  short* w_out = wbase + 328192;
  short* w_f1  = wbase + 459264;
  short* w_f2  = wbase + 721408;
  short* w_pj  = wbase + 983552;
  float* qbuf  = (float*)(w8 + 136315904);      // (B*4096)
  float* scor  = (float*)(w8 + 136578048);      // (64,1024)
  float* ctxs  = (float*)(w8 + 136840192);      // (64,256)
  float* stats = (float*)(w8 + 136905728);      // 5 sites x 16 x 2 (640 B)
  float* uvb   = (float*)(w8 + 136906368);      // 2306 x 2 f32 (18448 B)
  float* alphB = (float*)(w8 + 136924816);      // 16 f32 (reused per site)
  float* betaB = (float*)(w8 + 136924928);      // 16x512 f32 = 32 KB (reused)

  cvt6_k<<<4098, 256, 0, stream>>>(pw_w, qkv_w, out_w, ffn1_w, ffn2_w, proj_w,
                                   gn1_g, gn2_g, gnf_g, wbase, stats);
  fold_k<<<2306, 64, 0, stream>>>(qkv_w, ffn1_w, proj_w,
                                  gn1_g, gn1_b, gn2_g, gn2_b, gnf_g, gnf_b, uvb);

  dwconv_k<<<dim3(256,16), 256, 0, stream>>>(x, dw_w, dw_g, dw_b, dw_m, dw_v, bufB);
  transpose_k<<<dim3(64,4,16), 256, 0, stream>>>(bufB, bufA);

  // pw conv -> P (stats site 0 = gn1 layer 0)
  gemm_k<0,256,0,0><<<dim3(32,2,16), 256, 0, stream>>>(w_pw, bufA, 256, nullptr, P,
      nullptr, nullptr, nullptr, nullptr, nullptr, nullptr, stats + 0,
      nullptr, nullptr);

  for (int i = 0; i < 2; ++i){
    float* st1 = stats + (i == 0 ? 0 : 2)*32;            // gn1 site
    beta0_k<<<dim3(2,16), 256, 0, stream>>>(qkv_b + i*513 + 1,
        uvb + (size_t)(i*513+1)*2, st1, 512, betaB, alphB);
    q_k<<<16384, 256, 0, stream>>>(P, qkv_w + (size_t)i*513*256, gn1_g + i*256,
        qkv_b + i*513, uvb + (size_t)(i*513)*2, st1, qbuf);
    gemm_k<1,256,1,1><<<dim3(32,4,16), 256, 0, stream>>>(w_qkv + (i*513+1)*256, P, 512,
        nullptr, nullptr, bufB, nullptr, nullptr, nullptr, nullptr, nullptr,
        nullptr, alphB, betaB);
    softmax_k<<<64, 256, 0, stream>>>(qbuf, scor, ctxs);
    ctx_k<<<dim3(64,4), 256, 0, stream>>>(bufB, scor, ctxs);
    attn_in_k<<<16384, 256, 0, stream>>>(bufB, ctxs, bufA);
    // out proj: P += (unpermute), stats -> gn2 site
    gemm_k<5,256,0,0><<<dim3(32,2,16), 256, 0, stream>>>(w_out + i*65536, bufA, 256,
        out_b + i*256, P, nullptr, nullptr, nullptr, nullptr, nullptr, nullptr,
        stats + (i == 0 ? 1 : 3)*32, nullptr, nullptr);
    float* st2 = stats + (i == 0 ? 1 : 3)*32;
    beta0_k<<<dim3(2,16), 256, 0, stream>>>(ffn1_b + i*512,
        uvb + (size_t)(1026 + i*512)*2, st2, 512, betaB, alphB);
    gemm_k<3,256,1,0><<<dim3(32,4,16), 256, 0, stream>>>(w_f1 + i*131072, P, 512,
        nullptr, nullptr, bufB, nullptr, nullptr, nullptr, nullptr, nullptr,
        nullptr, alphB, betaB);
    // ffn2: P += , stats -> next gn1 site (i=0) or gnf site (i=1)
    gemm_k<2,512,0,0><<<dim3(32,2,16), 256, 0, stream>>>(w_f2 + i*131072, bufB, 256,
        ffn2_b + i*256, P, nullptr, nullptr, nullptr, nullptr, nullptr, nullptr,
        stats + (i == 0 ? 2 : 4)*32, nullptr, nullptr);
  }

  beta4_k<<<16, 256, 0, stream>>>(pbn_g, pbn_b, pbn_m, pbn_v,
      uvb + (size_t)2050*2, stats + 4*32, betaB, betaB + 4096);
  gemm_k<4,256,1,0><<<dim3(32,2,16), 256, 0, stream>>>(w_pj, P, 256, nullptr,
      nullptr, nullptr, out, nullptr, nullptr, nullptr, nullptr, nullptr,
      betaB, betaB + 4096);

  (void)in_sizes; (void)n_in; (void)out_size; (void)ws_size;
}

// Round 7
// 581.918 us; speedup vs baseline: 1.1456x; 1.1109x over previous
//
#include <hip/hip_runtime.h>
#include <hip/hip_bf16.h>
#include <stdint.h>

// MobileViTBlockV2: B=16, C=256, H=W=64, D=256, F=512, L=2, patch 2x2.
// R11: base = R8 (verified 623.8us: GN folded in-GEMM, no beta pre-kernels;
// R10's 6 beta launches cost +23us and proved occupancy is NOT the bound).
// Change: f2b uses compiler-native __bf16 cast (backend packs pairs into
// v_cvt_pk_bf16_f32 — m240: compiler does this better than hand asm) and
// silu uses hw exp2+rcp (~4 ops vs libm expf+div). Attacks the 61% VALUBusy
// epilogue without touching the verified memory structure.

#define B_    16
#define C_    256
#define D_    256
#define NPIX  4096
#define NE_PB 1048576   // D_*NPIX elements per batch for GN

typedef __attribute__((ext_vector_type(8))) short  short8;
typedef __attribute__((ext_vector_type(4))) short  short4v;
typedef __attribute__((ext_vector_type(4))) float  f32x4;
typedef __attribute__((ext_vector_type(2))) float  f32x2;

__device__ __forceinline__ float b2f(short s){
  return __uint_as_float(((unsigned)(unsigned short)s) << 16);
}
// compiler-native f32->bf16 (RNE); backend emits v_cvt_pk_bf16_f32 for pairs
__device__ __forceinline__ short f2b(float f){
  __bf16 h = (__bf16)f;
  return *(short*)&h;
}
__device__ __forceinline__ float silu_f(float x){
  float e = __builtin_amdgcn_exp2f(-1.44269504f * x);   // exp(-x)
  return x * __builtin_amdgcn_rcpf(1.f + e);
}

__device__ __forceinline__ void gld16(const short* g, short* l){
  __builtin_amdgcn_global_load_lds(
      (const __attribute__((address_space(1))) void*)g,
      (__attribute__((address_space(3))) void*)l, 16, 0, 0);
}

// pi (parity-permuted) -> pixel: pi = parity*1024 + (h/2)*32 + (w/2)
__device__ __forceinline__ int pi2pix(int n){
  int p = n >> 10, idx = n & 1023;
  int h = ((idx >> 5) << 1) | (p >> 1);
  int w = ((idx & 31) << 1) | (p & 1);
  return h*64 + w;
}

// ---------- all weight casts (g-scaled at fold sites) + stats zero ----------
__global__ void cvt6_k(const float* __restrict__ s0, const float* __restrict__ s1,
                       const float* __restrict__ s2, const float* __restrict__ s3,
                       const float* __restrict__ s4, const float* __restrict__ s5,
                       const float* __restrict__ g1, const float* __restrict__ g2,
                       const float* __restrict__ gf,
                       short* __restrict__ dst, float* __restrict__ stats){
  const int i = blockIdx.x*256 + threadIdx.x;
  if (blockIdx.x == 0 && threadIdx.x < 160) stats[threadIdx.x] = 0.f;
  if (i >= 1049088) return;
  float v;
  if      (i <  65536){ v = s0[i]; }                                    // pw
  else if (i < 328192){ int j = i -  65536;                             // qkv (fold gn1)
                        v = s1[j] * g1[(j/131328)*256 + (j & 255)]; }
  else if (i < 459264){ v = s2[i - 328192]; }                           // out
  else if (i < 721408){ int j = i - 459264;                             // ffn1 (fold gn2)
                        v = s3[j] * g2[(j >> 17)*256 + (j & 255)]; }
  else if (i < 983552){ v = s4[i - 721408]; }                           // ffn2
  else               { int j = i - 983552;                              // proj (fold gnf)
                        v = s5[j] * gf[j & 255]; }
  dst[i] = f2b(v);
}

// ---------- per-site u = W.g, v = W.b  (one wave per output row) ----------
// rows: [0,1026) qkv L0/L1 (513 each, row0=q) ; [1026,2050) ffn1 L0/L1 ;
// [2050,2306) proj. uv[row*2] = u, uv[row*2+1] = v.
__global__ void fold_k(const float* __restrict__ qkvw, const float* __restrict__ f1w,
                       const float* __restrict__ pjw,
                       const float* __restrict__ g1, const float* __restrict__ b1,
                       const float* __restrict__ g2, const float* __restrict__ b2,
                       const float* __restrict__ gf, const float* __restrict__ bf,
                       float* __restrict__ uv){
  const int row = blockIdx.x;
  const int l = threadIdx.x;
  const float* W; const float* g; const float* bb;
  if (row < 1026){ int layer = row/513, o = row - layer*513;
    W = qkvw + (size_t)(layer*513 + o)*256; g = g1 + layer*256; bb = b1 + layer*256; }
  else if (row < 2050){ int r2 = row - 1026; int layer = r2 >> 9, o = r2 & 511;
    W = f1w + (size_t)(layer*512 + o)*256; g = g2 + layer*256; bb = b2 + layer*256; }
  else { int o = row - 2050; W = pjw + (size_t)o*256; g = gf; bb = bf; }
  float u = 0.f, v = 0.f;
#pragma unroll
  for (int k = 0; k < 4; ++k){
    const int c = l + k*64;
    const float w = W[c];
    u += w * g[c]; v += w * bb[c];
  }
#pragma unroll
  for (int o = 32; o > 0; o >>= 1){ u += __shfl_down(u, o); v += __shfl_down(v, o); }
  if (l == 0){ uv[row*2] = u; uv[row*2+1] = v; }
}

// ---------- dwconv3x3 + BN + SiLU: one block per (b,c) plane ----------
__global__ __launch_bounds__(256)
void dwconv_k(const float* __restrict__ X, const float* __restrict__ W,
              const float* __restrict__ G, const float* __restrict__ Bb,
              const float* __restrict__ Mn, const float* __restrict__ Vr,
              short* __restrict__ O){
  const int c = blockIdx.x, b = blockIdx.y;
  const int t = threadIdx.x;
  __shared__ float xs[66][68];
  // halo zero
  if (t < 132){ int r = (t >= 66) ? 65 : 0; int cc = (t >= 66) ? t-66 : t; xs[r][cc] = 0.f; }
  if (t < 128){ int r = 1 + (t & 63); int cc = (t >> 6) ? 65 : 0; xs[r][cc] = 0.f; }
  const float* xp = X + ((size_t)(b*C_ + c)) * NPIX;
#pragma unroll
  for (int it = 0; it < 4; ++it){
    const int idx = it*256 + t;
    const int row = idx >> 4, cq = idx & 15;
    f32x4 v = *(const f32x4*)&xp[row*64 + cq*4];
    xs[row+1][cq*4+1] = v.x; xs[row+1][cq*4+2] = v.y;
    xs[row+1][cq*4+3] = v.z; xs[row+1][cq*4+4] = v.w;
  }
  float wgt[9];
#pragma unroll
  for (int j = 0; j < 9; ++j) wgt[j] = W[c*9 + j];
  const float scale = G[c] * rsqrtf(Vr[c] + 1e-5f);
  const float mu = Mn[c], bb = Bb[c];
  __syncthreads();
  const int tr = t >> 4, tc = t & 15;
  float win[6][6];
#pragma unroll
  for (int dr = 0; dr < 6; ++dr){
    f32x4 a = *(const f32x4*)&xs[tr*4+dr][tc*4];
    f32x2 bq = *(const f32x2*)&xs[tr*4+dr][tc*4+4];
    win[dr][0] = a.x; win[dr][1] = a.y; win[dr][2] = a.z; win[dr][3] = a.w;
    win[dr][4] = bq.x; win[dr][5] = bq.y;
  }
  short* op = O + ((size_t)(b*C_ + c)) * NPIX;
#pragma unroll
  for (int jr = 0; jr < 4; ++jr){
    short4v o;
#pragma unroll
    for (int jc = 0; jc < 4; ++jc){
      float s = 0.f;
#pragma unroll
      for (int dh = 0; dh < 3; ++dh)
#pragma unroll
        for (int dw = 0; dw < 3; ++dw)
          s += win[jr+dh][jc+dw] * wgt[dh*3+dw];
      float y = (s - mu) * scale + bb;
      o[jc] = f2b(silu_f(y));
    }
    *(short4v*)&op[(tr*4+jr)*64 + tc*4] = o;
  }
}

// ---------- (b,c,s) -> (b,s,c) bf16 transpose, 64x64 tiles, vector both sides ----------
__global__ void transpose_k(const short* __restrict__ I, short* __restrict__ O){
  const int s0 = blockIdx.x*64, c0 = blockIdx.y*64, b = blockIdx.z;
  const int t = threadIdx.x;
  __shared__ short tile[64][68];   // [s_local][c_local]
  const int hi = t >> 4, lo = t & 15;
#pragma unroll
  for (int cy = 0; cy < 4; ++cy){
    const int cl = cy*16 + hi;
    short4v v = *(const short4v*)&I[((size_t)(b*C_ + c0 + cl))*NPIX + s0 + lo*4];
    tile[lo*4+0][cl] = v.x; tile[lo*4+1][cl] = v.y;
    tile[lo*4+2][cl] = v.z; tile[lo*4+3][cl] = v.w;
  }
  __syncthreads();
#pragma unroll
  for (int py = 0; py < 4; ++py){
    const int pl = py*16 + hi;
    short4v v = *(const short4v*)&tile[pl][lo*4];
    *(short4v*)&O[((size_t)(b*NPIX + s0 + pl))*C_ + c0 + lo*4] = v;
  }
}

// ---------- MFMA bf16 GEMM: D[pix][chan] = sum_k X[pix][k]*Wt[chan][k] ----------
// Tile 128 pix x 128 chan, BK=64. W is the MFMA A operand (chan on reg axis).
// EPI: 0 = P(bf16)=acc (+stats); 1 = bf16 Obf = acc+bias;
// 2 = P += acc+bias (+stats); 3 = bf16 Obf = silu(acc+bias);
// 4 = f32 NCHW Of32 = BN(acc); 5 = P += acc+bias at pi2pix(row) (+stats)
// FOLD: GN folded input — epilogue out = acc*inv + (bias + v - inv*mu*u).
// GATHER: stage X rows at pi2pix(row) (per-lane global address).
template<int EPI, int K, int FOLD, int GATHER>
__global__ __launch_bounds__(256, 3)
void gemm_k(const short* __restrict__ Wt, const short* __restrict__ X,
            const int M,
            const float* __restrict__ bias,
            short* __restrict__ P,
            short* __restrict__ Obf,
            float* __restrict__ Of32,
            const float* __restrict__ bng, const float* __restrict__ bnb,
            const float* __restrict__ bnm, const float* __restrict__ bnv,
            float* __restrict__ st,
            const float* __restrict__ uv, const float* __restrict__ stIn)
{
  constexpr int S = K / 64;
  const int nt = blockIdx.x;          // pixel tile (128)
  const int ct = blockIdx.y;          // chan tile (128)
  const int b  = blockIdx.z;
  const int tid = threadIdx.x;
  const int ln = tid & 63, wv = tid >> 6;
  const int wx = wv & 1;              // chan half (64)
  const int wy = wv >> 1;             // pixel half (64)
  const int lr = ln & 15, lq = ln >> 4;
  const int rl = ln >> 3, sp = ln & 7;
  const int sw = sp ^ rl;             // staged k-seg (XOR swizzle)

  __shared__ __align__(16) char smem[33824];
  short* As = (short*)smem;            // W tile: 128 chan rows x 64 k (16 KB)
  short* Xs = (short*)(smem + 16384);  // X tile: 128 pix rows x 64 k (16 KB)
  float* CT = (float*)smem;            // epilogue restage (64x132 f32)
  float* red = (float*)(smem + 33792); // 8 floats

  const short* Wp = Wt + (size_t)(ct*128)*K;
  const short* Xp = X + ((size_t)b*NPIX + (size_t)nt*128) * K;

  const short* gw[4]; const short* gx[4]; short* lw[4]; short* lx[4];
#pragma unroll
  for (int j = 0; j < 4; ++j){
    const int row = 32*wv + 8*j + rl;
    gw[j] = Wp + (size_t)row*K + sw*8;
    if constexpr (GATHER)
      gx[j] = X + ((size_t)b*NPIX + pi2pix(nt*128 + row))*K + sw*8;
    else
      gx[j] = Xp + (size_t)row*K + sw*8;
    lw[j] = As + (4*wv + j)*512;
    lx[j] = Xs + (4*wv + j)*512;
  }

  f32x4 acc[4][4];
#pragma unroll
  for (int r = 0; r < 4; ++r)
#pragma unroll
    for (int c = 0; c < 4; ++c) acc[r][c] = (f32x4){0.f,0.f,0.f,0.f};

  for (int stp = 0; stp < S; ++stp){
    if (stp) __syncthreads();
#pragma unroll
    for (int j = 0; j < 4; ++j) gld16(gw[j] + stp*64, lw[j]);
#pragma unroll
    for (int j = 0; j < 4; ++j) gld16(gx[j] + stp*64, lx[j]);
    __syncthreads();
#pragma unroll
    for (int kk = 0; kk < 2; ++kk){
      const int seg = ((kk*4 + lq) ^ (lr & 7)) * 16;   // byte offset in 128B row
      short8 aw[4], bx[4];
#pragma unroll
      for (int r = 0; r < 4; ++r)
        aw[r] = *(const short8*)((const char*)As + (wx*64 + r*16 + lr)*128 + seg);
#pragma unroll
      for (int c = 0; c < 4; ++c)
        bx[c] = *(const short8*)((const char*)Xs + (wy*64 + c*16 + lr)*128 + seg);
#pragma unroll
      for (int r = 0; r < 4; ++r)
#pragma unroll
        for (int c = 0; c < 4; ++c)
          acc[r][c] = __builtin_amdgcn_mfma_f32_16x16x32_bf16(aw[r], bx[c], acc[r][c], 0, 0, 0);
    }
  }
  // acc[r][c]: chan = ct*128 + wx*64 + r*16 + lq*4 + reg ; pix = nt*128 + wy*64 + c*16 + lr

  const int ch8 = (tid & 15) * 8;      // store-phase chan offset within 128
  float s_mul = 1.f;
  f32x4 be0 = (f32x4){0.f,0.f,0.f,0.f}, be1 = be0;
  if constexpr (EPI == 1 || EPI == 2 || EPI == 3 || EPI == 5){
    be0 = *(const f32x4*)&bias[ct*128 + ch8];
    be1 = *(const f32x4*)&bias[ct*128 + ch8 + 4];
  }
  if constexpr (FOLD && EPI != 4){
    const float mean = stIn[b*2]   * (1.f/NE_PB);
    const float m2   = stIn[b*2+1] * (1.f/NE_PB);
    const float inv  = rsqrtf(m2 - mean*mean + 1e-5f);
    s_mul = inv;
    const float muinv = mean * inv;
    const float* up = &uv[(size_t)(ct*128 + ch8)*2];
#pragma unroll
    for (int k = 0; k < 4; ++k){
      f32x2 p0 = *(const f32x2*)&up[k*2];       // chan ch8+k   : (u,v)
      f32x2 p1 = *(const f32x2*)&up[8 + k*2];   // chan ch8+4+k : (u,v)
      be0[k] += p0.y - muinv*p0.x;
      be1[k] += p1.y - muinv*p1.x;
    }
  }

  float sm = 0.f, ss = 0.f;

  if constexpr (EPI != 4){
    // 2 passes over pixel halves; CT[pixL 0..63][chan 0..127], stride 132
#pragma unroll
    for (int p = 0; p < 2; ++p){
      __syncthreads();
      if (wy == p){
#pragma unroll
        for (int r = 0; r < 4; ++r)
#pragma unroll
          for (int c = 0; c < 4; ++c)
            *(f32x4*)&CT[(c*16 + lr)*132 + wx*64 + r*16 + lq*4] = acc[r][c];
      }
      __syncthreads();
#pragma unroll
      for (int it = 0; it < 4; ++it){
        const int pixL = it*16 + (tid >> 4);
        f32x4 v0 = *(const f32x4*)&CT[pixL*132 + ch8];
        f32x4 v1 = *(const f32x4*)&CT[pixL*132 + ch8 + 4];
        if constexpr (EPI != 0){
          v0.x = v0.x*s_mul + be0.x; v0.y = v0.y*s_mul + be0.y;
          v0.z = v0.z*s_mul + be0.z; v0.w = v0.w*s_mul + be0.w;
          v1.x = v1.x*s_mul + be1.x; v1.y = v1.y*s_mul + be1.y;
          v1.z = v1.z*s_mul + be1.z; v1.w = v1.w*s_mul + be1.w;
        }
        int pixg = nt*128 + p*64 + pixL;
        if constexpr (EPI == 5) pixg = pi2pix(pixg);
        const size_t rowb = (size_t)b*NPIX + pixg;
        if constexpr (EPI == 0){
          short8 o;
          o[0]=f2b(v0.x); o[1]=f2b(v0.y); o[2]=f2b(v0.z); o[3]=f2b(v0.w);
          o[4]=f2b(v1.x); o[5]=f2b(v1.y); o[6]=f2b(v1.z); o[7]=f2b(v1.w);
          *(short8*)&P[rowb*256 + ct*128 + ch8] = o;
          sm += v0.x+v0.y+v0.z+v0.w + v1.x+v1.y+v1.z+v1.w;
          ss += v0.x*v0.x+v0.y*v0.y+v0.z*v0.z+v0.w*v0.w
              + v1.x*v1.x+v1.y*v1.y+v1.z*v1.z+v1.w*v1.w;
        } else if constexpr (EPI == 2 || EPI == 5){
          short* pp = &P[rowb*256 + ct*128 + ch8];
          short8 old = *(const short8*)pp;
          float n0 = b2f(old[0])+v0.x, n1 = b2f(old[1])+v0.y;
          float n2 = b2f(old[2])+v0.z, n3 = b2f(old[3])+v0.w;
          float n4 = b2f(old[4])+v1.x, n5 = b2f(old[5])+v1.y;
          float n6 = b2f(old[6])+v1.z, n7 = b2f(old[7])+v1.w;
          short8 o;
          o[0]=f2b(n0); o[1]=f2b(n1); o[2]=f2b(n2); o[3]=f2b(n3);
          o[4]=f2b(n4); o[5]=f2b(n5); o[6]=f2b(n6); o[7]=f2b(n7);
          *(short8*)pp = o;
          sm += n0+n1+n2+n3+n4+n5+n6+n7;
          ss += n0*n0+n1*n1+n2*n2+n3*n3+n4*n4+n5*n5+n6*n6+n7*n7;
        } else if constexpr (EPI == 1){
          short8 o;
          o[0]=f2b(v0.x); o[1]=f2b(v0.y); o[2]=f2b(v0.z); o[3]=f2b(v0.w);
          o[4]=f2b(v1.x); o[5]=f2b(v1.y); o[6]=f2b(v1.z); o[7]=f2b(v1.w);
          *(short8*)&Obf[rowb*(size_t)M + ct*128 + ch8] = o;
        } else {  // EPI == 3
          short8 o;
          o[0]=f2b(silu_f(v0.x)); o[1]=f2b(silu_f(v0.y));
          o[2]=f2b(silu_f(v0.z)); o[3]=f2b(silu_f(v0.w));
          o[4]=f2b(silu_f(v1.x)); o[5]=f2b(silu_f(v1.y));
          o[6]=f2b(silu_f(v1.z)); o[7]=f2b(silu_f(v1.w));
          *(short8*)&Obf[rowb*(size_t)M + ct*128 + ch8] = o;
        }
      }
    }
    if constexpr (EPI == 0 || EPI == 2 || EPI == 5){
#pragma unroll
      for (int o = 32; o > 0; o >>= 1){ sm += __shfl_down(sm, o); ss += __shfl_down(ss, o); }
      if (ln == 0){ red[wv*2] = sm; red[wv*2+1] = ss; }
      __syncthreads();
      if (tid == 0){
        atomicAdd(&st[b*2+0], red[0]+red[2]+red[4]+red[6]);
        atomicAdd(&st[b*2+1], red[1]+red[3]+red[5]+red[7]);
      }
    }
  } else {
    // EPI 4: BN (+FOLD) -> f32 NCHW; 2 passes over chan halves; CT[chanL][pix]
    float muinv4 = 0.f;
    if constexpr (FOLD){
      const float mean = stIn[b*2]   * (1.f/NE_PB);
      const float m2   = stIn[b*2+1] * (1.f/NE_PB);
      const float inv  = rsqrtf(m2 - mean*mean + 1e-5f);
      s_mul = inv;
      muinv4 = mean * inv;
    }
#pragma unroll
    for (int p = 0; p < 2; ++p){
      __syncthreads();
      if (wx == p){
#pragma unroll
        for (int r = 0; r < 4; ++r)
#pragma unroll
          for (int c = 0; c < 4; ++c){
            const int pixL = wy*64 + c*16 + lr;
#pragma unroll
            for (int j = 0; j < 4; ++j)
              CT[(r*16 + lq*4 + j)*132 + pixL] = acc[r][c][j];
          }
      }
      __syncthreads();
#pragma unroll
      for (int it = 0; it < 8; ++it){
        const int idx = it*256 + tid;
        const int chL = idx >> 5, pq = (idx & 31)*4;
        const int chan = ct*128 + p*64 + chL;
        f32x4 v = *(const f32x4*)&CT[chL*132 + pq];
        const float sc = bng[chan] * rsqrtf(bnv[chan] + 1e-5f);
        const float mu = bnm[chan], bb = bnb[chan];
        float A = sc, Bc = -mu*sc + bb;
        if constexpr (FOLD){
          f32x2 uvp = *(const f32x2*)&uv[(size_t)chan*2];
          A = s_mul * sc;
          Bc = ((uvp.y - muinv4*uvp.x) - mu)*sc + bb;
        }
        f32x4 o;
        o.x = v.x*A + Bc; o.y = v.y*A + Bc;
        o.z = v.z*A + Bc; o.w = v.w*A + Bc;
        *(f32x4*)&Of32[((size_t)(b*C_ + chan))*NPIX + (size_t)nt*128 + pq] = o;
      }
    }
  }
}

// ---------- q = inv*(Wq.g . p) + (qb + vq - inv*mu*uq)  (gathered pi rows) ----------
__global__ void q_k(const short* __restrict__ P, const float* __restrict__ Wq,
                    const float* __restrict__ Gg, const float* __restrict__ Qb,
                    const float* __restrict__ uv, const float* __restrict__ stIn,
                    float* __restrict__ Q){
  const int lane = threadIdx.x & 63;
  const int pix = (blockIdx.x*256 + threadIdx.x) >> 6;   // b*4096 + pi
  const int b = pix >> 12, pi = pix & 4095;
  const int prow = pi2pix(pi);
  short4v u4 = *(const short4v*)&P[((size_t)b*NPIX + prow)*256 + lane*4];
  f32x4  w4 = *(const f32x4*)&Wq[lane*4];
  f32x4  g4 = *(const f32x4*)&Gg[lane*4];
  float s = b2f(u4.x)*w4.x*g4.x + b2f(u4.y)*w4.y*g4.y
          + b2f(u4.z)*w4.z*g4.z + b2f(u4.w)*w4.w*g4.w;
#pragma unroll
  for (int o = 32; o > 0; o >>= 1) s += __shfl_down(s, o);
  if (lane == 0){
    const float mean = stIn[b*2]   * (1.f/NE_PB);
    const float m2   = stIn[b*2+1] * (1.f/NE_PB);
    const float inv  = rsqrtf(m2 - mean*mean + 1e-5f);
    Q[pix] = inv*s + Qb[0] + uv[1] - inv*mean*uv[0];
  }
}

// ---------- softmax over 1024 contiguous pi-pixels; also zeroes ctx accum ----------
__global__ void softmax_k(const float* __restrict__ Q, float* __restrict__ S,
                          float* __restrict__ CT){
  const int bp = blockIdx.x;
  const int t = threadIdx.x;
  CT[bp*256 + t] = 0.f;
  float vals[4];
  float mx = -1e30f;
#pragma unroll
  for (int j = 0; j < 4; ++j){
    vals[j] = Q[bp*1024 + t + j*256];
    mx = fmaxf(mx, vals[j]);
  }
  __shared__ float red[4];
  const int lane = t & 63, wv = t >> 6;
#pragma unroll
  for (int o = 32; o > 0; o >>= 1) mx = fmaxf(mx, __shfl_down(mx, o));
  if (lane == 0) red[wv] = mx;
  __syncthreads();
  mx = fmaxf(fmaxf(red[0], red[1]), fmaxf(red[2], red[3]));
  __syncthreads();
  float sum = 0.f;
#pragma unroll
  for (int j = 0; j < 4; ++j){ vals[j] = expf(vals[j] - mx); sum += vals[j]; }
#pragma unroll
  for (int o = 32; o > 0; o >>= 1) sum += __shfl_down(sum, o);
  if (lane == 0) red[wv] = sum;
  __syncthreads();
  sum = red[0] + red[1] + red[2] + red[3];
  const float r = 1.f / sum;
#pragma unroll
  for (int j = 0; j < 4; ++j) S[bp*1024 + t + j*256] = vals[j]*r;
}

// ---------- ctx[bp][c] = sum_n k[bp*1024+n][c] * s[bp][n]  (coalesced, atomics) ----------
__global__ void ctx_k(const short* __restrict__ KV, const float* __restrict__ S,
                      float* __restrict__ CT){
  const int bp = blockIdx.x, ch = blockIdx.y;
  const int ln = threadIdx.x & 63, wv = threadIdx.x >> 6;
  const int j0 = ch*256 + wv*64;
  f32x4 acc = (f32x4){0.f,0.f,0.f,0.f};
  for (int jj = 0; jj < 64; jj += 4){
    f32x4 s4 = *(const f32x4*)&S[bp*1024 + j0 + jj];
#pragma unroll
    for (int u = 0; u < 4; ++u){
      short4v kv = *(const short4v*)&KV[((size_t)bp*1024 + j0 + jj + u)*512 + ln*4];
      const float s = s4[u];
      acc.x += b2f(kv.x)*s; acc.y += b2f(kv.y)*s;
      acc.z += b2f(kv.z)*s; acc.w += b2f(kv.w)*s;
    }
  }
  atomicAdd(&CT[bp*256 + ln*4 + 0], acc.x);
  atomicAdd(&CT[bp*256 + ln*4 + 1], acc.y);
  atomicAdd(&CT[bp*256 + ln*4 + 2], acc.z);
  atomicAdd(&CT[bp*256 + ln*4 + 3], acc.w);
}

// ---------- attn input: relu(v) * ctx[parity]  (all pi-ordered) ----------
__global__ void attn_in_k(const short* __restrict__ KV, const float* __restrict__ CT,
                          short* __restrict__ O){
  const size_t vid = (size_t)blockIdx.x*256 + threadIdx.x;
  const int c4 = (int)(vid & 63);
  const size_t r = vid >> 6;
  const int bp = (int)(r >> 10);
  short4v v4 = *(const short4v*)&KV[r*512 + 256 + c4*4];
  f32x4  cx = *(const f32x4*)&CT[bp*256 + c4*4];
  short4v o;
  o.x = f2b(fmaxf(b2f(v4.x), 0.f)*cx.x);
  o.y = f2b(fmaxf(b2f(v4.y), 0.f)*cx.y);
  o.z = f2b(fmaxf(b2f(v4.z), 0.f)*cx.z);
  o.w = f2b(fmaxf(b2f(v4.w), 0.f)*cx.w);
  *(short4v*)&O[r*256 + c4*4] = o;
}

extern "C" void kernel_launch(void* const* d_in, const int* in_sizes, int n_in,
                              void* d_out, int out_size, void* d_ws, size_t ws_size,
                              hipStream_t stream){
  const float* x      = (const float*)d_in[0];
  const float* dw_w   = (const float*)d_in[1];
  const float* dw_g   = (const float*)d_in[2];
  const float* dw_b   = (const float*)d_in[3];
  const float* dw_m   = (const float*)d_in[4];
  const float* dw_v   = (const float*)d_in[5];
  const float* pw_w   = (const float*)d_in[6];
  const float* gn1_g  = (const float*)d_in[7];
  const float* gn1_b  = (const float*)d_in[8];
  const float* qkv_w  = (const float*)d_in[9];
  const float* qkv_b  = (const float*)d_in[10];
  const float* out_w  = (const float*)d_in[11];
  const float* out_b  = (const float*)d_in[12];
  const float* gn2_g  = (const float*)d_in[13];
  const float* gn2_b  = (const float*)d_in[14];
  const float* ffn1_w = (const float*)d_in[15];
  const float* ffn1_b = (const float*)d_in[16];
  const float* ffn2_w = (const float*)d_in[17];
  const float* ffn2_b = (const float*)d_in[18];
  const float* gnf_g  = (const float*)d_in[19];
  const float* gnf_b  = (const float*)d_in[20];
  const float* proj_w = (const float*)d_in[21];
  const float* pbn_g  = (const float*)d_in[22];
  const float* pbn_b  = (const float*)d_in[23];
  const float* pbn_m  = (const float*)d_in[24];
  const float* pbn_v  = (const float*)d_in[25];
  float* out = (float*)d_out;

  uint8_t* w8 = (uint8_t*)d_ws;
  short* P     = (short*)(w8);                  // bf16 residual, 32 MiB
  short* bufA  = (short*)(w8 + 33554432);       // bf16 (B,4096,256), 32 MiB
  short* bufB  = (short*)(w8 + 67108864);       // bf16 (B,4096,512), 64 MiB
  short* wbase = (short*)(w8 + 134217728);      // all weights bf16, contiguous
  short* w_pw  = wbase;
  short* w_qkv = wbase + 65536;
  short* w_out = wbase + 328192;
  short* w_f1  = wbase + 459264;
  short* w_f2  = wbase + 721408;
  short* w_pj  = wbase + 983552;
  float* qbuf  = (float*)(w8 + 136315904);      // (B*4096)
  float* scor  = (float*)(w8 + 136578048);      // (64,1024)
  float* ctxs  = (float*)(w8 + 136840192);      // (64,256)
  float* stats = (float*)(w8 + 136905728);      // 5 sites x 16 x 2 (640 B)
  float* uvb   = (float*)(w8 + 136906368);      // 2306 x 2 f32 (18448 B)

  cvt6_k<<<4098, 256, 0, stream>>>(pw_w, qkv_w, out_w, ffn1_w, ffn2_w, proj_w,
                                   gn1_g, gn2_g, gnf_g, wbase, stats);
  fold_k<<<2306, 64, 0, stream>>>(qkv_w, ffn1_w, proj_w,
                                  gn1_g, gn1_b, gn2_g, gn2_b, gnf_g, gnf_b, uvb);

  dwconv_k<<<dim3(256,16), 256, 0, stream>>>(x, dw_w, dw_g, dw_b, dw_m, dw_v, bufB);
  transpose_k<<<dim3(64,4,16), 256, 0, stream>>>(bufB, bufA);

  // pw conv -> P (stats site 0 = gn1 layer 0)
  gemm_k<0,256,0,0><<<dim3(32,2,16), 256, 0, stream>>>(w_pw, bufA, 256, nullptr, P,
      nullptr, nullptr, nullptr, nullptr, nullptr, nullptr, stats + 0,
      nullptr, nullptr);

  for (int i = 0; i < 2; ++i){
    float* st1 = stats + (i == 0 ? 0 : 2)*32;            // gn1 site
    q_k<<<16384, 256, 0, stream>>>(P, qkv_w + (size_t)i*513*256, gn1_g + i*256,
        qkv_b + i*513, uvb + (size_t)(i*513)*2, st1, qbuf);
    gemm_k<1,256,1,1><<<dim3(32,4,16), 256, 0, stream>>>(w_qkv + (i*513+1)*256, P, 512,
        qkv_b + i*513 + 1, nullptr, bufB, nullptr, nullptr, nullptr, nullptr, nullptr,
        nullptr, uvb + (size_t)(i*513+1)*2, st1);
    softmax_k<<<64, 256, 0, stream>>>(qbuf, scor, ctxs);
    ctx_k<<<dim3(64,4), 256, 0, stream>>>(bufB, scor, ctxs);
    attn_in_k<<<16384, 256, 0, stream>>>(bufB, ctxs, bufA);
    // out proj: P += (unpermute), stats -> gn2 site
    gemm_k<5,256,0,0><<<dim3(32,2,16), 256, 0, stream>>>(w_out + i*65536, bufA, 256,
        out_b + i*256, P, nullptr, nullptr, nullptr, nullptr, nullptr, nullptr,
        stats + (i == 0 ? 1 : 3)*32, nullptr, nullptr);
    float* st2 = stats + (i == 0 ? 1 : 3)*32;
    gemm_k<3,256,1,0><<<dim3(32,4,16), 256, 0, stream>>>(w_f1 + i*131072, P, 512,
        ffn1_b + i*512, nullptr, bufB, nullptr, nullptr, nullptr, nullptr, nullptr,
        nullptr, uvb + (size_t)(1026 + i*512)*2, st2);
    // ffn2: P += , stats -> next gn1 site (i=0) or gnf site (i=1)
    gemm_k<2,512,0,0><<<dim3(32,2,16), 256, 0, stream>>>(w_f2 + i*131072, bufB, 256,
        ffn2_b + i*256, P, nullptr, nullptr, nullptr, nullptr, nullptr, nullptr,
        stats + (i == 0 ? 2 : 4)*32, nullptr, nullptr);
  }

  gemm_k<4,256,1,0><<<dim3(32,2,16), 256, 0, stream>>>(w_pj, P, 256, nullptr,
      nullptr, nullptr, out, pbn_g, pbn_b, pbn_m, pbn_v, nullptr,
      uvb + (size_t)2050*2, stats + 4*32);

  (void)in_sizes; (void)n_in; (void)out_size; (void)ws_size;
}

// Round 9
// 561.517 us; speedup vs baseline: 1.1872x; 1.0363x over previous
//
#include <hip/hip_runtime.h>
#include <hip/hip_bf16.h>
#include <stdint.h>

// MobileViTBlockV2: B=16, C=256, H=W=64, D=256, F=512, L=2, patch 2x2.
// R12 (resubmit; previous round was a broker infra failure, kernel never ran).
// Base = R11 (verified 581.9us). P now lives in pi-order for the whole
// middle section: pw gathers bufA at pi2pix and writes P linearly; qkv/q_k/
// ffn1 read P linearly (gathers dropped); out-proj is a LINEAR RMW (old EPI5
// scattered RMW eliminated); proj gathers P at pix2pi so NCHW stays contiguous.
// EPI2 additionally prefetches the RMW 'old' P values into registers before
// the K-loop so the ~900cy load latency hides under compute instead of
// serializing the store loop. GEMM core / staging / restage untouched.

#define B_    16
#define C_    256
#define D_    256
#define NPIX  4096
#define NE_PB 1048576   // D_*NPIX elements per batch for GN

typedef __attribute__((ext_vector_type(8))) short  short8;
typedef __attribute__((ext_vector_type(4))) short  short4v;
typedef __attribute__((ext_vector_type(4))) float  f32x4;
typedef __attribute__((ext_vector_type(2))) float  f32x2;

__device__ __forceinline__ float b2f(short s){
  return __uint_as_float(((unsigned)(unsigned short)s) << 16);
}
// compiler-native f32->bf16 (RNE); backend packs pairs into v_cvt_pk_bf16_f32
__device__ __forceinline__ short f2b(float f){
  __bf16 h = (__bf16)f;
  return *(short*)&h;
}
__device__ __forceinline__ float silu_f(float x){
  float e = __builtin_amdgcn_exp2f(-1.44269504f * x);   // exp(-x)
  return x * __builtin_amdgcn_rcpf(1.f + e);
}

__device__ __forceinline__ void gld16(const short* g, short* l){
  __builtin_amdgcn_global_load_lds(
      (const __attribute__((address_space(1))) void*)g,
      (__attribute__((address_space(3))) void*)l, 16, 0, 0);
}

// pi (parity-permuted) <-> pixel: pi = parity*1024 + (h/2)*32 + (w/2)
__device__ __forceinline__ int pi2pix(int n){
  int p = n >> 10, idx = n & 1023;
  int h = ((idx >> 5) << 1) | (p >> 1);
  int w = ((idx & 31) << 1) | (p & 1);
  return h*64 + w;
}
__device__ __forceinline__ int pix2pi(int pix){
  int h = pix >> 6, w = pix & 63;
  return ((h & 1)*2 + (w & 1))*1024 + (h >> 1)*32 + (w >> 1);
}

// ---------- all weight casts (g-scaled at fold sites) + stats zero ----------
__global__ void cvt6_k(const float* __restrict__ s0, const float* __restrict__ s1,
                       const float* __restrict__ s2, const float* __restrict__ s3,
                       const float* __restrict__ s4, const float* __restrict__ s5,
                       const float* __restrict__ g1, const float* __restrict__ g2,
                       const float* __restrict__ gf,
                       short* __restrict__ dst, float* __restrict__ stats){
  const int i = blockIdx.x*256 + threadIdx.x;
  if (blockIdx.x == 0 && threadIdx.x < 160) stats[threadIdx.x] = 0.f;
  if (i >= 1049088) return;
  float v;
  if      (i <  65536){ v = s0[i]; }                                    // pw
  else if (i < 328192){ int j = i -  65536;                             // qkv (fold gn1)
                        v = s1[j] * g1[(j/131328)*256 + (j & 255)]; }
  else if (i < 459264){ v = s2[i - 328192]; }                           // out
  else if (i < 721408){ int j = i - 459264;                             // ffn1 (fold gn2)
                        v = s3[j] * g2[(j >> 17)*256 + (j & 255)]; }
  else if (i < 983552){ v = s4[i - 721408]; }                           // ffn2
  else               { int j = i - 983552;                              // proj (fold gnf)
                        v = s5[j] * gf[j & 255]; }
  dst[i] = f2b(v);
}

// ---------- per-site u = W.g, v = W.b  (one wave per output row) ----------
// rows: [0,1026) qkv L0/L1 (513 each, row0=q) ; [1026,2050) ffn1 L0/L1 ;
// [2050,2306) proj. uv[row*2] = u, uv[row*2+1] = v.
__global__ void fold_k(const float* __restrict__ qkvw, const float* __restrict__ f1w,
                       const float* __restrict__ pjw,
                       const float* __restrict__ g1, const float* __restrict__ b1,
                       const float* __restrict__ g2, const float* __restrict__ b2,
                       const float* __restrict__ gf, const float* __restrict__ bf,
                       float* __restrict__ uv){
  const int row = blockIdx.x;
  const int l = threadIdx.x;
  const float* W; const float* g; const float* bb;
  if (row < 1026){ int layer = row/513, o = row - layer*513;
    W = qkvw + (size_t)(layer*513 + o)*256; g = g1 + layer*256; bb = b1 + layer*256; }
  else if (row < 2050){ int r2 = row - 1026; int layer = r2 >> 9, o = r2 & 511;
    W = f1w + (size_t)(layer*512 + o)*256; g = g2 + layer*256; bb = b2 + layer*256; }
  else { int o = row - 2050; W = pjw + (size_t)o*256; g = gf; bb = bf; }
  float u = 0.f, v = 0.f;
#pragma unroll
  for (int k = 0; k < 4; ++k){
    const int c = l + k*64;
    const float w = W[c];
    u += w * g[c]; v += w * bb[c];
  }
#pragma unroll
  for (int o = 32; o > 0; o >>= 1){ u += __shfl_down(u, o); v += __shfl_down(v, o); }
  if (l == 0){ uv[row*2] = u; uv[row*2+1] = v; }
}

// ---------- dwconv3x3 + BN + SiLU: one block per (b,c) plane ----------
__global__ __launch_bounds__(256)
void dwconv_k(const float* __restrict__ X, const float* __restrict__ W,
              const float* __restrict__ G, const float* __restrict__ Bb,
              const float* __restrict__ Mn, const float* __restrict__ Vr,
              short* __restrict__ O){
  const int c = blockIdx.x, b = blockIdx.y;
  const int t = threadIdx.x;
  __shared__ float xs[66][68];
  // halo zero
  if (t < 132){ int r = (t >= 66) ? 65 : 0; int cc = (t >= 66) ? t-66 : t; xs[r][cc] = 0.f; }
  if (t < 128){ int r = 1 + (t & 63); int cc = (t >> 6) ? 65 : 0; xs[r][cc] = 0.f; }
  const float* xp = X + ((size_t)(b*C_ + c)) * NPIX;
#pragma unroll
  for (int it = 0; it < 4; ++it){
    const int idx = it*256 + t;
    const int row = idx >> 4, cq = idx & 15;
    f32x4 v = *(const f32x4*)&xp[row*64 + cq*4];
    xs[row+1][cq*4+1] = v.x; xs[row+1][cq*4+2] = v.y;
    xs[row+1][cq*4+3] = v.z; xs[row+1][cq*4+4] = v.w;
  }
  float wgt[9];
#pragma unroll
  for (int j = 0; j < 9; ++j) wgt[j] = W[c*9 + j];
  const float scale = G[c] * rsqrtf(Vr[c] + 1e-5f);
  const float mu = Mn[c], bb = Bb[c];
  __syncthreads();
  const int tr = t >> 4, tc = t & 15;
  float win[6][6];
#pragma unroll
  for (int dr = 0; dr < 6; ++dr){
    f32x4 a = *(const f32x4*)&xs[tr*4+dr][tc*4];
    f32x2 bq = *(const f32x2*)&xs[tr*4+dr][tc*4+4];
    win[dr][0] = a.x; win[dr][1] = a.y; win[dr][2] = a.z; win[dr][3] = a.w;
    win[dr][4] = bq.x; win[dr][5] = bq.y;
  }
  short* op = O + ((size_t)(b*C_ + c)) * NPIX;
#pragma unroll
  for (int jr = 0; jr < 4; ++jr){
    short4v o;
#pragma unroll
    for (int jc = 0; jc < 4; ++jc){
      float s = 0.f;
#pragma unroll
      for (int dh = 0; dh < 3; ++dh)
#pragma unroll
        for (int dw = 0; dw < 3; ++dw)
          s += win[jr+dh][jc+dw] * wgt[dh*3+dw];
      float y = (s - mu) * scale + bb;
      o[jc] = f2b(silu_f(y));
    }
    *(short4v*)&op[(tr*4+jr)*64 + tc*4] = o;
  }
}

// ---------- (b,c,s) -> (b,s,c) bf16 transpose, 64x64 tiles, vector both sides ----------
__global__ void transpose_k(const short* __restrict__ I, short* __restrict__ O){
  const int s0 = blockIdx.x*64, c0 = blockIdx.y*64, b = blockIdx.z;
  const int t = threadIdx.x;
  __shared__ short tile[64][68];   // [s_local][c_local]
  const int hi = t >> 4, lo = t & 15;
#pragma unroll
  for (int cy = 0; cy < 4; ++cy){
    const int cl = cy*16 + hi;
    short4v v = *(const short4v*)&I[((size_t)(b*C_ + c0 + cl))*NPIX + s0 + lo*4];
    tile[lo*4+0][cl] = v.x; tile[lo*4+1][cl] = v.y;
    tile[lo*4+2][cl] = v.z; tile[lo*4+3][cl] = v.w;
  }
  __syncthreads();
#pragma unroll
  for (int py = 0; py < 4; ++py){
    const int pl = py*16 + hi;
    short4v v = *(const short4v*)&tile[pl][lo*4];
    *(short4v*)&O[((size_t)(b*NPIX + s0 + pl))*C_ + c0 + lo*4] = v;
  }
}

// ---------- MFMA bf16 GEMM: D[row][chan] = sum_k X[xrow][k]*Wt[chan][k] ----------
// Tile 128 rows x 128 chan, BK=64. W is the MFMA A operand (chan on reg axis).
// EPI: 0 = P(bf16)=acc (+stats); 1 = bf16 Obf = acc(+fold);
// 2 = P += acc+bias, old-P PREFETCHED pre-K-loop (+stats);
// 3 = bf16 Obf = silu(acc(+fold)); 4 = f32 NCHW Of32 = (fold+)BN(acc)
// FOLD: GN folded input — epilogue out = acc*inv + (bias + v - inv*mu*u).
// GATHER: 0 = linear X rows; 1 = stage X rows at pi2pix(row); 2 = at pix2pi(row).
template<int EPI, int K, int FOLD, int GATHER>
__global__ __launch_bounds__(256, 3)
void gemm_k(const short* __restrict__ Wt, const short* __restrict__ X,
            const int M,
            const float* __restrict__ bias,
            short* __restrict__ P,
            short* __restrict__ Obf,
            float* __restrict__ Of32,
            const float* __restrict__ bng, const float* __restrict__ bnb,
            const float* __restrict__ bnm, const float* __restrict__ bnv,
            float* __restrict__ st,
            const float* __restrict__ uv, const float* __restrict__ stIn)
{
  constexpr int S = K / 64;
  const int nt = blockIdx.x;          // row tile (128)
  const int ct = blockIdx.y;          // chan tile (128)
  const int b  = blockIdx.z;
  const int tid = threadIdx.x;
  const int ln = tid & 63, wv = tid >> 6;
  const int wx = wv & 1;              // chan half (64)
  const int wy = wv >> 1;             // row half (64)
  const int lr = ln & 15, lq = ln >> 4;
  const int rl = ln >> 3, sp = ln & 7;
  const int sw = sp ^ rl;             // staged k-seg (XOR swizzle)
  const int ch8 = (tid & 15) * 8;     // store-phase chan offset within 128

  __shared__ __align__(16) char smem[33824];
  short* As = (short*)smem;            // W tile: 128 chan rows x 64 k (16 KB)
  short* Xs = (short*)(smem + 16384);  // X tile: 128 rows x 64 k (16 KB)
  float* CT = (float*)smem;            // epilogue restage (64x132 f32)
  float* red = (float*)(smem + 33792); // 8 floats

  const short* Wp = Wt + (size_t)(ct*128)*K;
  const short* Xp = X + ((size_t)b*NPIX + (size_t)nt*128) * K;

  const short* gw[4]; const short* gx[4]; short* lw[4]; short* lx[4];
#pragma unroll
  for (int j = 0; j < 4; ++j){
    const int row = 32*wv + 8*j + rl;
    gw[j] = Wp + (size_t)row*K + sw*8;
    if constexpr (GATHER == 1)
      gx[j] = X + ((size_t)b*NPIX + pi2pix(nt*128 + row))*K + sw*8;
    else if constexpr (GATHER == 2)
      gx[j] = X + ((size_t)b*NPIX + pix2pi(nt*128 + row))*K + sw*8;
    else
      gx[j] = Xp + (size_t)row*K + sw*8;
    lw[j] = As + (4*wv + j)*512;
    lx[j] = Xs + (4*wv + j)*512;
  }

  // EPI2: prefetch RMW old-P into registers; latency hides under the K-loop.
  short8 oldv[2][4];
  if constexpr (EPI == 2){
#pragma unroll
    for (int p = 0; p < 2; ++p)
#pragma unroll
      for (int it = 0; it < 4; ++it){
        const int pixL = it*16 + (tid >> 4);
        const size_t rowb = (size_t)b*NPIX + nt*128 + p*64 + pixL;
        oldv[p][it] = *(const short8*)&P[rowb*256 + ct*128 + ch8];
      }
  }

  f32x4 acc[4][4];
#pragma unroll
  for (int r = 0; r < 4; ++r)
#pragma unroll
    for (int c = 0; c < 4; ++c) acc[r][c] = (f32x4){0.f,0.f,0.f,0.f};

  for (int stp = 0; stp < S; ++stp){
    if (stp) __syncthreads();
#pragma unroll
    for (int j = 0; j < 4; ++j) gld16(gw[j] + stp*64, lw[j]);
#pragma unroll
    for (int j = 0; j < 4; ++j) gld16(gx[j] + stp*64, lx[j]);
    __syncthreads();
#pragma unroll
    for (int kk = 0; kk < 2; ++kk){
      const int seg = ((kk*4 + lq) ^ (lr & 7)) * 16;   // byte offset in 128B row
      short8 aw[4], bx[4];
#pragma unroll
      for (int r = 0; r < 4; ++r)
        aw[r] = *(const short8*)((const char*)As + (wx*64 + r*16 + lr)*128 + seg);
#pragma unroll
      for (int c = 0; c < 4; ++c)
        bx[c] = *(const short8*)((const char*)Xs + (wy*64 + c*16 + lr)*128 + seg);
#pragma unroll
      for (int r = 0; r < 4; ++r)
#pragma unroll
        for (int c = 0; c < 4; ++c)
          acc[r][c] = __builtin_amdgcn_mfma_f32_16x16x32_bf16(aw[r], bx[c], acc[r][c], 0, 0, 0);
    }
  }
  // acc[r][c]: chan = ct*128 + wx*64 + r*16 + lq*4 + reg ; row = nt*128 + wy*64 + c*16 + lr

  float s_mul = 1.f;
  f32x4 be0 = (f32x4){0.f,0.f,0.f,0.f}, be1 = be0;
  if constexpr (EPI == 1 || EPI == 2 || EPI == 3){
    if constexpr (!FOLD){
      be0 = *(const f32x4*)&bias[ct*128 + ch8];
      be1 = *(const f32x4*)&bias[ct*128 + ch8 + 4];
    }
  }
  if constexpr (FOLD && EPI != 4){
    const float mean = stIn[b*2]   * (1.f/NE_PB);
    const float m2   = stIn[b*2+1] * (1.f/NE_PB);
    const float inv  = rsqrtf(m2 - mean*mean + 1e-5f);
    s_mul = inv;
    const float muinv = mean * inv;
    const float* up = &uv[(size_t)(ct*128 + ch8)*2];
#pragma unroll
    for (int k = 0; k < 4; ++k){
      f32x2 p0 = *(const f32x2*)&up[k*2];       // chan ch8+k   : (u,v)
      f32x2 p1 = *(const f32x2*)&up[8 + k*2];   // chan ch8+4+k : (u,v)
      be0[k] += p0.y - muinv*p0.x;
      be1[k] += p1.y - muinv*p1.x;
    }
    if constexpr (EPI == 1 || EPI == 2 || EPI == 3){
      if (bias){
        f32x4 bb0 = *(const f32x4*)&bias[ct*128 + ch8];
        f32x4 bb1 = *(const f32x4*)&bias[ct*128 + ch8 + 4];
        be0.x += bb0.x; be0.y += bb0.y; be0.z += bb0.z; be0.w += bb0.w;
        be1.x += bb1.x; be1.y += bb1.y; be1.z += bb1.z; be1.w += bb1.w;
      }
    }
  }

  float sm = 0.f, ss = 0.f;

  if constexpr (EPI != 4){
    // 2 passes over row halves; CT[rowL 0..63][chan 0..127], stride 132
#pragma unroll
    for (int p = 0; p < 2; ++p){
      __syncthreads();
      if (wy == p){
#pragma unroll
        for (int r = 0; r < 4; ++r)
#pragma unroll
          for (int c = 0; c < 4; ++c)
            *(f32x4*)&CT[(c*16 + lr)*132 + wx*64 + r*16 + lq*4] = acc[r][c];
      }
      __syncthreads();
#pragma unroll
      for (int it = 0; it < 4; ++it){
        const int pixL = it*16 + (tid >> 4);
        f32x4 v0 = *(const f32x4*)&CT[pixL*132 + ch8];
        f32x4 v1 = *(const f32x4*)&CT[pixL*132 + ch8 + 4];
        if constexpr (EPI != 0){
          v0.x = v0.x*s_mul + be0.x; v0.y = v0.y*s_mul + be0.y;
          v0.z = v0.z*s_mul + be0.z; v0.w = v0.w*s_mul + be0.w;
          v1.x = v1.x*s_mul + be1.x; v1.y = v1.y*s_mul + be1.y;
          v1.z = v1.z*s_mul + be1.z; v1.w = v1.w*s_mul + be1.w;
        }
        const int pixg = nt*128 + p*64 + pixL;
        const size_t rowb = (size_t)b*NPIX + pixg;
        if constexpr (EPI == 0){
          short8 o;
          o[0]=f2b(v0.x); o[1]=f2b(v0.y); o[2]=f2b(v0.z); o[3]=f2b(v0.w);
          o[4]=f2b(v1.x); o[5]=f2b(v1.y); o[6]=f2b(v1.z); o[7]=f2b(v1.w);
          *(short8*)&P[rowb*256 + ct*128 + ch8] = o;
          sm += v0.x+v0.y+v0.z+v0.w + v1.x+v1.y+v1.z+v1.w;
          ss += v0.x*v0.x+v0.y*v0.y+v0.z*v0.z+v0.w*v0.w
              + v1.x*v1.x+v1.y*v1.y+v1.z*v1.z+v1.w*v1.w;
        } else if constexpr (EPI == 2){
          short8 old = oldv[p][it];
          float n0 = b2f(old[0])+v0.x, n1 = b2f(old[1])+v0.y;
          float n2 = b2f(old[2])+v0.z, n3 = b2f(old[3])+v0.w;
          float n4 = b2f(old[4])+v1.x, n5 = b2f(old[5])+v1.y;
          float n6 = b2f(old[6])+v1.z, n7 = b2f(old[7])+v1.w;
          short8 o;
          o[0]=f2b(n0); o[1]=f2b(n1); o[2]=f2b(n2); o[3]=f2b(n3);
          o[4]=f2b(n4); o[5]=f2b(n5); o[6]=f2b(n6); o[7]=f2b(n7);
          *(short8*)&P[rowb*256 + ct*128 + ch8] = o;
          sm += n0+n1+n2+n3+n4+n5+n6+n7;
          ss += n0*n0+n1*n1+n2*n2+n3*n3+n4*n4+n5*n5+n6*n6+n7*n7;
        } else if constexpr (EPI == 1){
          short8 o;
          o[0]=f2b(v0.x); o[1]=f2b(v0.y); o[2]=f2b(v0.z); o[3]=f2b(v0.w);
          o[4]=f2b(v1.x); o[5]=f2b(v1.y); o[6]=f2b(v1.z); o[7]=f2b(v1.w);
          *(short8*)&Obf[rowb*(size_t)M + ct*128 + ch8] = o;
        } else {  // EPI == 3
          short8 o;
          o[0]=f2b(silu_f(v0.x)); o[1]=f2b(silu_f(v0.y));
          o[2]=f2b(silu_f(v0.z)); o[3]=f2b(silu_f(v0.w));
          o[4]=f2b(silu_f(v1.x)); o[5]=f2b(silu_f(v1.y));
          o[6]=f2b(silu_f(v1.z)); o[7]=f2b(silu_f(v1.w));
          *(short8*)&Obf[rowb*(size_t)M + ct*128 + ch8] = o;
        }
      }
    }
    if constexpr (EPI == 0 || EPI == 2){
#pragma unroll
      for (int o = 32; o > 0; o >>= 1){ sm += __shfl_down(sm, o); ss += __shfl_down(ss, o); }
      if (ln == 0){ red[wv*2] = sm; red[wv*2+1] = ss; }
      __syncthreads();
      if (tid == 0){
        atomicAdd(&st[b*2+0], red[0]+red[2]+red[4]+red[6]);
        atomicAdd(&st[b*2+1], red[1]+red[3]+red[5]+red[7]);
      }
    }
  } else {
    // EPI 4: BN (+FOLD) -> f32 NCHW; 2 passes over chan halves; CT[chanL][pix]
    float muinv4 = 0.f;
    if constexpr (FOLD){
      const float mean = stIn[b*2]   * (1.f/NE_PB);
      const float m2   = stIn[b*2+1] * (1.f/NE_PB);
      const float inv  = rsqrtf(m2 - mean*mean + 1e-5f);
      s_mul = inv;
      muinv4 = mean * inv;
    }
#pragma unroll
    for (int p = 0; p < 2; ++p){
      __syncthreads();
      if (wx == p){
#pragma unroll
        for (int r = 0; r < 4; ++r)
#pragma unroll
          for (int c = 0; c < 4; ++c){
            const int pixL = wy*64 + c*16 + lr;
#pragma unroll
            for (int j = 0; j < 4; ++j)
              CT[(r*16 + lq*4 + j)*132 + pixL] = acc[r][c][j];
          }
      }
      __syncthreads();
#pragma unroll
      for (int it = 0; it < 8; ++it){
        const int idx = it*256 + tid;
        const int chL = idx >> 5, pq = (idx & 31)*4;
        const int chan = ct*128 + p*64 + chL;
        f32x4 v = *(const f32x4*)&CT[chL*132 + pq];
        const float sc = bng[chan] * rsqrtf(bnv[chan] + 1e-5f);
        const float mu = bnm[chan], bb = bnb[chan];
        float A = sc, Bc = -mu*sc + bb;
        if constexpr (FOLD){
          f32x2 uvp = *(const f32x2*)&uv[(size_t)chan*2];
          A = s_mul * sc;
          Bc = ((uvp.y - muinv4*uvp.x) - mu)*sc + bb;
        }
        f32x4 o;
        o.x = v.x*A + Bc; o.y = v.y*A + Bc;
        o.z = v.z*A + Bc; o.w = v.w*A + Bc;
        *(f32x4*)&Of32[((size_t)(b*C_ + chan))*NPIX + (size_t)nt*128 + pq] = o;
      }
    }
  }
}

// ---------- q = inv*(Wq.g . p) + (qb + vq - inv*mu*uq)  (P already pi-order) ----------
__global__ void q_k(const short* __restrict__ P, const float* __restrict__ Wq,
                    const float* __restrict__ Gg, const float* __restrict__ Qb,
                    const float* __restrict__ uv, const float* __restrict__ stIn,
                    float* __restrict__ Q){
  const int lane = threadIdx.x & 63;
  const int pix = (blockIdx.x*256 + threadIdx.x) >> 6;   // b*4096 + pi
  const int b = pix >> 12;
  short4v u4 = *(const short4v*)&P[(size_t)pix*256 + lane*4];
  f32x4  w4 = *(const f32x4*)&Wq[lane*4];
  f32x4  g4 = *(const f32x4*)&Gg[lane*4];
  float s = b2f(u4.x)*w4.x*g4.x + b2f(u4.y)*w4.y*g4.y
          + b2f(u4.z)*w4.z*g4.z + b2f(u4.w)*w4.w*g4.w;
#pragma unroll
  for (int o = 32; o > 0; o >>= 1) s += __shfl_down(s, o);
  if (lane == 0){
    const float mean = stIn[b*2]   * (1.f/NE_PB);
    const float m2   = stIn[b*2+1] * (1.f/NE_PB);
    const float inv  = rsqrtf(m2 - mean*mean + 1e-5f);
    Q[pix] = inv*s + Qb[0] + uv[1] - inv*mean*uv[0];
  }
}

// ---------- softmax over 1024 contiguous pi-pixels; also zeroes ctx accum ----------
__global__ void softmax_k(const float* __restrict__ Q, float* __restrict__ S,
                          float* __restrict__ CT){
  const int bp = blockIdx.x;
  const int t = threadIdx.x;
  CT[bp*256 + t] = 0.f;
  float vals[4];
  float mx = -1e30f;
#pragma unroll
  for (int j = 0; j < 4; ++j){
    vals[j] = Q[bp*1024 + t + j*256];
    mx = fmaxf(mx, vals[j]);
  }
  __shared__ float red[4];
  const int lane = t & 63, wv = t >> 6;
#pragma unroll
  for (int o = 32; o > 0; o >>= 1) mx = fmaxf(mx, __shfl_down(mx, o));
  if (lane == 0) red[wv] = mx;
  __syncthreads();
  mx = fmaxf(fmaxf(red[0], red[1]), fmaxf(red[2], red[3]));
  __syncthreads();
  float sum = 0.f;
#pragma unroll
  for (int j = 0; j < 4; ++j){ vals[j] = expf(vals[j] - mx); sum += vals[j]; }
#pragma unroll
  for (int o = 32; o > 0; o >>= 1) sum += __shfl_down(sum, o);
  if (lane == 0) red[wv] = sum;
  __syncthreads();
  sum = red[0] + red[1] + red[2] + red[3];
  const float r = 1.f / sum;
#pragma unroll
  for (int j = 0; j < 4; ++j) S[bp*1024 + t + j*256] = vals[j]*r;
}

// ---------- ctx[bp][c] = sum_n k[bp*1024+n][c] * s[bp][n]  (coalesced, atomics) ----------
__global__ void ctx_k(const short* __restrict__ KV, const float* __restrict__ S,
                      float* __restrict__ CT){
  const int bp = blockIdx.x, ch = blockIdx.y;
  const int ln = threadIdx.x & 63, wv = threadIdx.x >> 6;
  const int j0 = ch*256 + wv*64;
  f32x4 acc = (f32x4){0.f,0.f,0.f,0.f};
  for (int jj = 0; jj < 64; jj += 4){
    f32x4 s4 = *(const f32x4*)&S[bp*1024 + j0 + jj];
#pragma unroll
    for (int u = 0; u < 4; ++u){
      short4v kv = *(const short4v*)&KV[((size_t)bp*1024 + j0 + jj + u)*512 + ln*4];
      const float s = s4[u];
      acc.x += b2f(kv.x)*s; acc.y += b2f(kv.y)*s;
      acc.z += b2f(kv.z)*s; acc.w += b2f(kv.w)*s;
    }
  }
  atomicAdd(&CT[bp*256 + ln*4 + 0], acc.x);
  atomicAdd(&CT[bp*256 + ln*4 + 1], acc.y);
  atomicAdd(&CT[bp*256 + ln*4 + 2], acc.z);
  atomicAdd(&CT[bp*256 + ln*4 + 3], acc.w);
}

// ---------- attn input: relu(v) * ctx[parity]  (all pi-ordered) ----------
__global__ void attn_in_k(const short* __restrict__ KV, const float* __restrict__ CT,
                          short* __restrict__ O){
  const size_t vid = (size_t)blockIdx.x*256 + threadIdx.x;
  const int c4 = (int)(vid & 63);
  const size_t r = vid >> 6;
  const int bp = (int)(r >> 10);
  short4v v4 = *(const short4v*)&KV[r*512 + 256 + c4*4];
  f32x4  cx = *(const f32x4*)&CT[bp*256 + c4*4];
  short4v o;
  o.x = f2b(fmaxf(b2f(v4.x), 0.f)*cx.x);
  o.y = f2b(fmaxf(b2f(v4.y), 0.f)*cx.y);
  o.z = f2b(fmaxf(b2f(v4.z), 0.f)*cx.z);
  o.w = f2b(fmaxf(b2f(v4.w), 0.f)*cx.w);
  *(short4v*)&O[r*256 + c4*4] = o;
}

extern "C" void kernel_launch(void* const* d_in, const int* in_sizes, int n_in,
                              void* d_out, int out_size, void* d_ws, size_t ws_size,
                              hipStream_t stream){
  const float* x      = (const float*)d_in[0];
  const float* dw_w   = (const float*)d_in[1];
  const float* dw_g   = (const float*)d_in[2];
  const float* dw_b   = (const float*)d_in[3];
  const float* dw_m   = (const float*)d_in[4];
  const float* dw_v   = (const float*)d_in[5];
  const float* pw_w   = (const float*)d_in[6];
  const float* gn1_g  = (const float*)d_in[7];
  const float* gn1_b  = (const float*)d_in[8];
  const float* qkv_w  = (const float*)d_in[9];
  const float* qkv_b  = (const float*)d_in[10];
  const float* out_w  = (const float*)d_in[11];
  const float* out_b  = (const float*)d_in[12];
  const float* gn2_g  = (const float*)d_in[13];
  const float* gn2_b  = (const float*)d_in[14];
  const float* ffn1_w = (const float*)d_in[15];
  const float* ffn1_b = (const float*)d_in[16];
  const float* ffn2_w = (const float*)d_in[17];
  const float* ffn2_b = (const float*)d_in[18];
  const float* gnf_g  = (const float*)d_in[19];
  const float* gnf_b  = (const float*)d_in[20];
  const float* proj_w = (const float*)d_in[21];
  const float* pbn_g  = (const float*)d_in[22];
  const float* pbn_b  = (const float*)d_in[23];
  const float* pbn_m  = (const float*)d_in[24];
  const float* pbn_v  = (const float*)d_in[25];
  float* out = (float*)d_out;

  uint8_t* w8 = (uint8_t*)d_ws;
  short* P     = (short*)(w8);                  // bf16 residual (pi-order), 32 MiB
  short* bufA  = (short*)(w8 + 33554432);       // bf16 (B,4096,256), 32 MiB
  short* bufB  = (short*)(w8 + 67108864);       // bf16 (B,4096,512), 64 MiB
  short* wbase = (short*)(w8 + 134217728);      // all weights bf16, contiguous
  short* w_pw  = wbase;
  short* w_qkv = wbase + 65536;
  short* w_out = wbase + 328192;
  short* w_f1  = wbase + 459264;
  short* w_f2  = wbase + 721408;
  short* w_pj  = wbase + 983552;
  float* qbuf  = (float*)(w8 + 136315904);      // (B*4096)
  float* scor  = (float*)(w8 + 136578048);      // (64,1024)
  float* ctxs  = (float*)(w8 + 136840192);      // (64,256)
  float* stats = (float*)(w8 + 136905728);      // 5 sites x 16 x 2 (640 B)
  float* uvb   = (float*)(w8 + 136906368);      // 2306 x 2 f32 (18448 B)

  cvt6_k<<<4098, 256, 0, stream>>>(pw_w, qkv_w, out_w, ffn1_w, ffn2_w, proj_w,
                                   gn1_g, gn2_g, gnf_g, wbase, stats);
  fold_k<<<2306, 64, 0, stream>>>(qkv_w, ffn1_w, proj_w,
                                  gn1_g, gn1_b, gn2_g, gn2_b, gnf_g, gnf_b, uvb);

  dwconv_k<<<dim3(256,16), 256, 0, stream>>>(x, dw_w, dw_g, dw_b, dw_m, dw_v, bufB);
  transpose_k<<<dim3(64,4,16), 256, 0, stream>>>(bufB, bufA);

  // pw conv -> P in pi-order (gather bufA rows at pi2pix); stats site 0
  gemm_k<0,256,0,1><<<dim3(32,2,16), 256, 0, stream>>>(w_pw, bufA, 256, nullptr, P,
      nullptr, nullptr, nullptr, nullptr, nullptr, nullptr, stats + 0,
      nullptr, nullptr);

  for (int i = 0; i < 2; ++i){
    float* st1 = stats + (i == 0 ? 0 : 2)*32;            // gn1 site
    q_k<<<16384, 256, 0, stream>>>(P, qkv_w + (size_t)i*513*256, gn1_g + i*256,
        qkv_b + i*513, uvb + (size_t)(i*513)*2, st1, qbuf);
    gemm_k<1,256,1,0><<<dim3(32,4,16), 256, 0, stream>>>(w_qkv + (i*513+1)*256, P, 512,
        qkv_b + i*513 + 1, nullptr, bufB, nullptr, nullptr, nullptr, nullptr, nullptr,
        nullptr, uvb + (size_t)(i*513+1)*2, st1);
    softmax_k<<<64, 256, 0, stream>>>(qbuf, scor, ctxs);
    ctx_k<<<dim3(64,4), 256, 0, stream>>>(bufB, scor, ctxs);
    attn_in_k<<<16384, 256, 0, stream>>>(bufB, ctxs, bufA);
    // out proj: P += (linear, pi-order), stats -> gn2 site
    gemm_k<2,256,0,0><<<dim3(32,2,16), 256, 0, stream>>>(w_out + i*65536, bufA, 256,
        out_b + i*256, P, nullptr, nullptr, nullptr, nullptr, nullptr, nullptr,
        stats + (i == 0 ? 1 : 3)*32, nullptr, nullptr);
    float* st2 = stats + (i == 0 ? 1 : 3)*32;
    gemm_k<3,256,1,0><<<dim3(32,4,16), 256, 0, stream>>>(w_f1 + i*131072, P, 512,
        ffn1_b + i*512, nullptr, bufB, nullptr, nullptr, nullptr, nullptr, nullptr,
        nullptr, uvb + (size_t)(1026 + i*512)*2, st2);
    // ffn2: P += , stats -> next gn1 site (i=0) or gnf site (i=1)
    gemm_k<2,512,0,0><<<dim3(32,2,16), 256, 0, stream>>>(w_f2 + i*131072, bufB, 256,
        ffn2_b + i*256, P, nullptr, nullptr, nullptr, nullptr, nullptr, nullptr,
        stats + (i == 0 ? 2 : 4)*32, nullptr, nullptr);
  }

  // proj: gather P rows at pix2pi -> NCHW f32 output stays contiguous
  gemm_k<4,256,1,2><<<dim3(32,2,16), 256, 0, stream>>>(w_pj, P, 256, nullptr,
      nullptr, nullptr, out, pbn_g, pbn_b, pbn_m, pbn_v, nullptr,
      uvb + (size_t)2050*2, stats + 4*32);

  (void)in_sizes; (void)n_in; (void)out_size; (void)ws_size;
}